// Round 9
// baseline (6455.553 us; speedup 1.0000x reference)
//
#include <hip/hip_runtime.h>
#include <hip/hip_bf16.h>
#include <math.h>

// ---------------------------------------------------------------------------
// DecoderTARDIS forward, fp32 — v7: 2-batch owners + deep MLP.
// R8 lesson (FETCH 7.6MB/step = full weight re-fetch): owner GEMV loops are
// latency-bound at ~700cy with 2 waves/SIMD and unroll 4. v7: 64 owners x
// 1024 threads (4 waves/SIMD) each handling 2 batches (every weight load
// feeds 2 FMAs), deep unrolls, logits tanh spread over 16 waves; A-blocks
// 1024 threads with k-split compute. Fence-free barrier kept (2/step).
// ---------------------------------------------------------------------------

static constexpr int LL   = 32;
static constexpr int BB   = 128;
static constexpr int ID   = 512;
static constexpr int HD   = 1024;
static constexpr int NS   = 512;
static constexpr int AA   = 128;
static constexpr int CCd  = 128;
static constexpr int AC   = 256;
static constexpr int WC   = 1344;           // 112 * 12
static constexpr int COL_W0  = 1024;
static constexpr int COL_G0  = 1280;
static constexpr int COL_AB0 = 1283;
static constexpr int COL_TAU = 1285;
static constexpr int NOWN = 64;             // owner blocks, 2 batches each
static constexpr int NAB  = 112;            // GEMM blocks, 12 cols each
static constexpr int GRID_P = NOWN + NAB;   // 176

// ------------------------------ threefry -----------------------------------
__device__ __forceinline__ uint32_t rotl32(uint32_t x, uint32_t r) {
  return (x << r) | (x >> (32u - r));
}

__device__ __forceinline__ void threefry2x32(uint32_t k0, uint32_t k1,
                                             uint32_t x0, uint32_t x1,
                                             uint32_t& o0, uint32_t& o1) {
  uint32_t ks0 = k0, ks1 = k1, ks2 = 0x1BD11BDAu ^ k0 ^ k1;
  x0 += ks0; x1 += ks1;
#define TFR(r) { x0 += x1; x1 = rotl32(x1, r); x1 ^= x0; }
  TFR(13u) TFR(15u) TFR(26u) TFR(6u)   x0 += ks1; x1 += ks2 + 1u;
  TFR(17u) TFR(29u) TFR(16u) TFR(24u)  x0 += ks2; x1 += ks0 + 2u;
  TFR(13u) TFR(15u) TFR(26u) TFR(6u)   x0 += ks0; x1 += ks1 + 3u;
  TFR(17u) TFR(29u) TFR(16u) TFR(24u)  x0 += ks1; x1 += ks2 + 4u;
  TFR(13u) TFR(15u) TFR(26u) TFR(6u)   x0 += ks2; x1 += ks0 + 5u;
#undef TFR
  o0 = x0; o1 = x1;
}

__device__ __forceinline__ float bits_to_gumbel(uint32_t bits) {
  uint32_t v = (bits >> 9) | 0x3F800000u;
  float f = __uint_as_float(v) - 1.0f;
  if (f <= 0.0f) f = 1.17549435e-38f;
  return -logf(-logf(f));
}

__device__ __forceinline__ float fast_tanh(float x) {
  float e = __expf(2.0f * x);
  return 1.0f - 2.0f / (e + 1.0f);
}

// --------------- coherent (agent-scope, relaxed) access helpers ------------
__device__ __forceinline__ float cohl(const float* p) {
  return __hip_atomic_load(p, __ATOMIC_RELAXED, __HIP_MEMORY_SCOPE_AGENT);
}
__device__ __forceinline__ void cohs(float* p, float v) {
  __hip_atomic_store(p, v, __ATOMIC_RELAXED, __HIP_MEMORY_SCOPE_AGENT);
}
__device__ __forceinline__ float2 cohl2(const float* p) {
  unsigned long long u = __hip_atomic_load((const unsigned long long*)p,
                                           __ATOMIC_RELAXED, __HIP_MEMORY_SCOPE_AGENT);
  float2 r; __builtin_memcpy(&r, &u, 8); return r;
}
__device__ __forceinline__ void cohs2(float* p, float2 v) {
  unsigned long long u; __builtin_memcpy(&u, &v, 8);
  __hip_atomic_store((unsigned long long*)p, u, __ATOMIC_RELAXED, __HIP_MEMORY_SCOPE_AGENT);
}

// ---------------- grid barrier: relaxed atomics + vmcnt drain --------------
__device__ __forceinline__ void gbar(unsigned int* cnt, unsigned int* flag,
                                     unsigned int& epoch) {
  asm volatile("s_waitcnt vmcnt(0)" ::: "memory");
  __syncthreads();
  if (threadIdx.x == 0) {
    epoch++;
    unsigned int old = __hip_atomic_fetch_add(cnt, 1u, __ATOMIC_RELAXED,
                                              __HIP_MEMORY_SCOPE_AGENT);
    if (old == epoch * GRID_P - 1u) {
      __hip_atomic_store(flag, epoch, __ATOMIC_RELAXED, __HIP_MEMORY_SCOPE_AGENT);
    } else {
      while (__hip_atomic_load(flag, __ATOMIC_RELAXED, __HIP_MEMORY_SCOPE_AGENT) < epoch) {
        __builtin_amdgcn_s_sleep(8);
      }
    }
  }
  __syncthreads();
}

// ------------------------------ prologue -----------------------------------
__global__ void pack_wcat(const float* __restrict__ Wh2c, const float* __restrict__ Wh2w,
                          const float* __restrict__ Wh2g, const float* __restrict__ Wh2ab,
                          const float* __restrict__ Wh2tau, float* __restrict__ Wcat) {
  int idx = blockIdx.x * blockDim.x + threadIdx.x;
  if (idx >= HD * WC) return;
  int k = idx / WC, c = idx % WC;
  float v = 0.0f;
  if (c < 1024)       v = Wh2c[(size_t)k * HD + c];
  else if (c < 1280)  v = Wh2w[(size_t)k * AC + (c - 1024)];
  else if (c < 1283)  v = Wh2g[k * 3 + (c - 1280)];
  else if (c < 1285)  v = Wh2ab[k * 2 + (c - 1283)];
  else if (c == 1285) v = Wh2tau[k];
  Wcat[idx] = v;
}

__global__ void addrw_kernel(const float* __restrict__ mem_bias,
                             const float* __restrict__ Wm2w,
                             float* __restrict__ addrW, float* __restrict__ addrWT) {
  int idx = blockIdx.x * blockDim.x + threadIdx.x;
  if (idx >= NS * AC) return;
  int n = idx / AC, m = idx % AC;
  float acc = 0.0f;
  for (int k = 0; k < AA; k++) acc += mem_bias[(size_t)n * AC + k] * Wm2w[(size_t)k * AC + m];
  addrW[(size_t)n * AC + m] = acc;
  addrWT[(size_t)m * NS + n] = acc;
}

__global__ void init_kernel(const float* __restrict__ hid, float* __restrict__ hbuf,
                            unsigned int* __restrict__ bar) {
  int idx = blockIdx.x * blockDim.x + threadIdx.x;
  if (idx < BB * HD) hbuf[idx] = hid[idx];
  if (idx < 512) bar[idx] = 0u;
}

// generic fp32 GEMM: C(M x Nw) = A(M x K) @ W(K x Nw); 128x64 tile, 8x4/thr
__global__ __launch_bounds__(256) void gemm_big(const float* __restrict__ A,
                                                const float* __restrict__ W,
                                                float* __restrict__ C,
                                                int K, int Nw) {
  __shared__ float sA[32][132];
  __shared__ float sB[32][68];
  const int tx = threadIdx.x & 15, ty = threadIdx.x >> 4;
  const int m0 = blockIdx.x * 128, n0 = blockIdx.y * 64;
  float acc[8][4] = {};
  for (int k0 = 0; k0 < K; k0 += 32) {
    for (int i = threadIdx.x; i < 128 * 32; i += 256) {
      int r = i >> 5, kk = i & 31;
      sA[kk][r] = A[(size_t)(m0 + r) * K + k0 + kk];
    }
    for (int i = threadIdx.x; i < 32 * 64; i += 256) {
      int kk = i >> 6, c = i & 63;
      sB[kk][c] = W[(size_t)(k0 + kk) * Nw + n0 + c];
    }
    __syncthreads();
#pragma unroll
    for (int kk = 0; kk < 32; ++kk) {
      float4 a0 = *(const float4*)&sA[kk][ty * 8];
      float4 a1 = *(const float4*)&sA[kk][ty * 8 + 4];
      float4 b0 = *(const float4*)&sB[kk][tx * 4];
      float ar[8] = {a0.x, a0.y, a0.z, a0.w, a1.x, a1.y, a1.z, a1.w};
      float br[4] = {b0.x, b0.y, b0.z, b0.w};
#pragma unroll
      for (int i2 = 0; i2 < 8; ++i2)
#pragma unroll
        for (int j2 = 0; j2 < 4; ++j2)
          acc[i2][j2] = fmaf(ar[i2], br[j2], acc[i2][j2]);
    }
    __syncthreads();
  }
#pragma unroll
  for (int i2 = 0; i2 < 8; ++i2) {
    float4 st = make_float4(acc[i2][0], acc[i2][1], acc[i2][2], acc[i2][3]);
    *(float4*)&C[(size_t)(m0 + ty * 8 + i2) * Nw + n0 + tx * 4] = st;
  }
}

// ------------------------------ persistent kernel --------------------------
struct AS {
  float w[12][1032];      // 49.5 KB Wcat slice
  float hst[128][68];     // 34.8 KB h chunk
  float red[1536];        // 6 KB k-split reduce
};
struct OS {
  float hL[2][HD], ccL[2][HD];
  float embL[2][ID], wsL[2][NS], zlL[2][NS];
  float u2wL[2][AC], biasL[2][AC], rsL[2][AC];
  float attL[AC];
  float vsL[2][CCd];
  float scratch[2048];
  int lwL[2][NS];
  int wpL[2][LL];
};
union SU { AS a; OS o; };

__global__ __launch_bounds__(1024) void persist_kernel(
    const float* __restrict__ inp, const float* __restrict__ hid,
    const float* __restrict__ mem_bias,
    const float* __restrict__ icatC, const float* __restrict__ icatW,
    const float* __restrict__ Wcat,
    const float* __restrict__ addrW, const float* __restrict__ addrWT,
    const float* __restrict__ atten,
    const float* __restrict__ Wi2g, const float* __restrict__ Wr2g,
    const float* __restrict__ Wi2ab, const float* __restrict__ Wr2ab,
    const float* __restrict__ Wr2c,
    const float* __restrict__ b_h2tau,
    const float* __restrict__ Wh2m, const float* __restrict__ Wm2w,
    const float* __restrict__ Wu2w,
    float* hbuf, float* hcat, float* valHistG, float* valWHistG,
    unsigned int* bar_cnt, unsigned int* bar_flag,
    float* __restrict__ out) {
  const int blk = blockIdx.x, tid = threadIdx.x;
  const int lane = tid & 63, wv = tid >> 6;       // 16 waves
  __shared__ SU sm;
  __shared__ float redv[16], redd[16]; __shared__ int redi[16];
  __shared__ float s_fio[2][3], s_ab[2][2], s_tau[2], s_zmax[2], s_ws[2];
  __shared__ int s_ns[2];
  unsigned int epoch = 0;

  uint32_t k1a, k1b, k2a, k2b;
  threefry2x32(0u, 42u, 0u, 0u, k1a, k1b);
  threefry2x32(0u, 42u, 0u, 1u, k2a, k2b);

  const bool owner = (blk < NOWN);
  const int b0 = blk * 2;                        // owner's batches b0, b0+1
  const int an0 = (blk - NOWN) * 12;             // A-block first col

  if (owner) {
    for (int i = tid; i < HD; i += 1024) {
      sm.o.hL[0][i] = hid[(size_t)b0 * HD + i];
      sm.o.hL[1][i] = hid[(size_t)(b0 + 1) * HD + i];
      sm.o.ccL[0][i] = 0.0f; sm.o.ccL[1][i] = 0.0f;
    }
    if (tid < NS) {
      sm.o.wsL[0][tid] = 0.0f; sm.o.wsL[1][tid] = 0.0f;
      sm.o.lwL[0][tid] = -1;   sm.o.lwL[1][tid] = -1;
    }
    if (tid < AC) {
      sm.o.attL[tid] = atten[tid];
      sm.o.u2wL[0][tid] = 0.0f; sm.o.u2wL[1][tid] = 0.0f;
    }
  } else {
    for (int i = tid; i < 12 * 1024; i += 1024) {
      int k = i / 12, c = i - k * 12;
      sm.a.w[c][k] = Wcat[(size_t)k * WC + an0 + c];
    }
  }
  __syncthreads();

  for (int t = 0; t < LL; ++t) {
    // ==================== window A ========================================
    if (!owner) {
      const int sub = (tid >> 7) & 1, t1 = tid & 127;
      const int cg = t1 & 3, rowg = t1 >> 2;
      float acc[4][3] = {};
      float2 pre[4];
#pragma unroll
      for (int ii = 0; ii < 4; ++ii) {
        int f = ii * 1024 + tid, r2 = f >> 5, k2 = f & 31;
        pre[ii] = cohl2(&hbuf[(size_t)r2 * HD + k2 * 2]);
      }
      for (int kc = 0; kc < HD; kc += 64) {
        __syncthreads();
#pragma unroll
        for (int ii = 0; ii < 4; ++ii) {
          int f = ii * 1024 + tid, r2 = f >> 5, k2 = f & 31;
          *(float2*)&sm.a.hst[r2][k2 * 2] = pre[ii];
        }
        __syncthreads();
        if (kc + 64 < HD) {
#pragma unroll
          for (int ii = 0; ii < 4; ++ii) {
            int f = ii * 1024 + tid, r2 = f >> 5, k2 = f & 31;
            pre[ii] = cohl2(&hbuf[(size_t)r2 * HD + kc + 64 + k2 * 2]);
          }
        }
        if (tid < 256) {
          const int k4lo = sub * 8;
#pragma unroll
          for (int k4 = k4lo; k4 < k4lo + 8; ++k4) {
            float4 w0 = *(const float4*)&sm.a.w[cg * 3 + 0][kc + k4 * 4];
            float4 w1 = *(const float4*)&sm.a.w[cg * 3 + 1][kc + k4 * 4];
            float4 w2 = *(const float4*)&sm.a.w[cg * 3 + 2][kc + k4 * 4];
#pragma unroll
            for (int j = 0; j < 4; ++j) {
              float4 h4 = *(const float4*)&sm.a.hst[rowg + 32 * j][k4 * 4];
              acc[j][0] = fmaf(h4.x, w0.x, fmaf(h4.y, w0.y, fmaf(h4.z, w0.z, fmaf(h4.w, w0.w, acc[j][0]))));
              acc[j][1] = fmaf(h4.x, w1.x, fmaf(h4.y, w1.y, fmaf(h4.z, w1.z, fmaf(h4.w, w1.w, acc[j][1]))));
              acc[j][2] = fmaf(h4.x, w2.x, fmaf(h4.y, w2.y, fmaf(h4.z, w2.z, fmaf(h4.w, w2.w, acc[j][2]))));
            }
          }
        }
      }
      __syncthreads();
      if (tid < 256 && sub == 1) {
#pragma unroll
        for (int j = 0; j < 4; ++j)
#pragma unroll
          for (int c = 0; c < 3; ++c)
            sm.a.red[t1 * 12 + j * 3 + c] = acc[j][c];
      }
      __syncthreads();
      if (tid < 128) {
#pragma unroll
        for (int j = 0; j < 4; ++j)
#pragma unroll
          for (int c = 0; c < 3; ++c)
            cohs(&hcat[(size_t)(rowg + 32 * j) * WC + an0 + cg * 3 + c],
                 acc[j][c] + sm.a.red[tid * 12 + j * 3 + c]);
      }
    } else {
      // owner A-window: emb, val/valW(t-1), u2w(t) — 2 batches, shared loads
      { int bq = tid >> 9, n = tid & 511;
        sm.o.embL[bq][n] = inp[((size_t)t * BB + b0 + bq) * ID + n]; }
      if (t > 0) {
        { int c = tid & 127, kq = tid >> 7;     // 8 k-groups of 128
          float a0 = 0, a1 = 0; int k0 = kq * 128;
#pragma unroll 8
          for (int k = k0; k < k0 + 128; ++k) {
            float w = Wh2m[(size_t)k * CCd + c];
            a0 = fmaf(sm.o.hL[0][k], w, a0); a1 = fmaf(sm.o.hL[1][k], w, a1);
          }
          sm.o.scratch[kq * 128 + c] = a0;
          sm.o.scratch[1024 + kq * 128 + c] = a1; }
        __syncthreads();
        if (tid < 256) {
          int bq = tid >> 7, c = tid & 127;
          float v = 0;
#pragma unroll
          for (int i = 0; i < 8; ++i) v += sm.o.scratch[bq * 1024 + i * 128 + c];
          sm.o.vsL[bq][c] = v;
          valHistG[((size_t)(b0 + bq) * LL + t - 1) * CCd + c] = v;
        }
        __syncthreads();
        { int m = tid & 255, cq = tid >> 8;     // 4 c-groups of 32
          float a0 = 0, a1 = 0; int c0 = cq * 32;
#pragma unroll 8
          for (int c = c0; c < c0 + 32; ++c) {
            float w = Wm2w[(size_t)(AA + c) * AC + m];
            a0 = fmaf(sm.o.vsL[0][c], w, a0); a1 = fmaf(sm.o.vsL[1][c], w, a1);
          }
          sm.o.scratch[cq * 256 + m] = a0;
          sm.o.scratch[1024 + cq * 256 + m] = a1; }
        __syncthreads();
        if (tid < 512) {
          int bq = tid >> 8, m = tid & 255;
          float v = 0;
#pragma unroll
          for (int i = 0; i < 4; ++i) v += sm.o.scratch[bq * 1024 + i * 256 + m];
          valWHistG[((size_t)(b0 + bq) * LL + t - 1) * AC + m] = v;
        }
        __syncthreads();
      }
      // u2w = LayerNorm(wsL) @ Wu2w, both batches
      {
        int bq = tid >> 9, n = tid & 511;
        float v = sm.o.wsL[bq][n];
        float s1 = v;
        for (int off = 32; off; off >>= 1) s1 += __shfl_down(s1, off, 64);
        if (lane == 0) redv[wv] = s1;
        __syncthreads();
        float mu = 0;
#pragma unroll
        for (int i = 0; i < 8; ++i) mu += redv[bq * 8 + i];
        mu /= (float)NS;
        float d = (v - mu) * (v - mu);
        for (int off = 32; off; off >>= 1) d += __shfl_down(d, off, 64);
        if (lane == 0) redd[wv] = d;
        __syncthreads();
        float var = 0;
#pragma unroll
        for (int i = 0; i < 8; ++i) var += redd[bq * 8 + i];
        var /= (float)NS;
        sm.o.zlL[bq][n] = (v - mu) * rsqrtf(var + 1e-5f);
      }
      __syncthreads();
      { int m = tid & 255, kq = tid >> 8;       // 4 k-groups of 128
        float a0 = 0, a1 = 0; int k0 = kq * 128;
#pragma unroll 8
        for (int k = k0; k < k0 + 128; ++k) {
          float w = Wu2w[(size_t)k * AC + m];
          a0 = fmaf(sm.o.zlL[0][k], w, a0); a1 = fmaf(sm.o.zlL[1][k], w, a1);
        }
        sm.o.scratch[kq * 256 + m] = a0;
        sm.o.scratch[1024 + kq * 256 + m] = a1; }
      __syncthreads();
      if (tid < 512) {
        int bq = tid >> 8, m = tid & 255;
        float v = 0;
#pragma unroll
        for (int i = 0; i < 4; ++i) v += sm.o.scratch[bq * 1024 + i * 256 + m];
        sm.o.u2wL[bq][m] = v;
      }
    }
    gbar(bar_cnt, bar_flag, epoch);

    // ==================== window LS (owners only) ==========================
    if (owner) {
      if (tid < 512) {
        int bq = tid >> 8, m = tid & 255;
        sm.o.biasL[bq][m] = cohl(&hcat[(size_t)(b0 + bq) * WC + COL_W0 + m]) +
                            icatW[((size_t)t * BB + b0 + bq) * AC + m] + sm.o.u2wL[bq][m];
      }
      __syncthreads();
      {  // logits: 512 n x 2 k-halves; one addrWT load feeds 2 batches
        int n = tid & 511, kh = tid >> 9;
        float a0 = 0, a1 = 0; int k0 = kh * 128;
        const float* awp = addrWT + n;
#pragma unroll 8
        for (int k = k0; k < k0 + 128; ++k) {
          float aw = awp[(size_t)k * NS], at = sm.o.attL[k];
          a0 = fmaf(fast_tanh(sm.o.biasL[0][k] + aw), at, a0);
          a1 = fmaf(fast_tanh(sm.o.biasL[1][k] + aw), at, a1);
        }
        sm.o.scratch[kh * 512 + n] = a0;
        sm.o.scratch[1024 + kh * 512 + n] = a1;
      }
      __syncthreads();
      { int bq = tid >> 9, n = tid & 511;
        sm.o.zlL[bq][n] = sm.o.scratch[bq * 1024 + n] + sm.o.scratch[bq * 1024 + 512 + n]; }
      __syncthreads();
      {  // corrections: 16 waves = 2 bq x 8 j-lanes
        int bq = wv >> 3;
        for (int j = wv & 7; j < t; j += 8) {
          int n2 = sm.o.wpL[bq][j];
          int s = sm.o.lwL[bq][n2];
          const float* dw = valWHistG + ((size_t)(b0 + bq) * LL + s) * AC;
          const float* aw = addrW + (size_t)n2 * AC;
          float q = 0;
#pragma unroll
          for (int k = lane; k < AC; k += 64)
            q = fmaf(fast_tanh(sm.o.biasL[bq][k] + aw[k] + dw[k]), sm.o.attL[k], q);
          for (int off = 32; off; off >>= 1) q += __shfl_down(q, off, 64);
          if (lane == 0) sm.o.zlL[bq][n2] = q;
        }
      }
      __syncthreads();
      const int bq = tid >> 9, n = tid & 511;
      float zg;
      { uint32_t gi = (uint32_t)(((size_t)t * BB + b0 + bq) * NS + n);
        uint32_t o0, o1; threefry2x32(k1a, k1b, 0u, gi, o0, o1);
        zg = sm.o.zlL[bq][n] + bits_to_gumbel(o0 ^ o1); }
      { float v = zg; int ix = n;
        for (int off = 32; off; off >>= 1) {
          float vo = __shfl_down(v, off, 64); int io = __shfl_down(ix, off, 64);
          if (vo > v || (vo == v && io < ix)) { v = vo; ix = io; }
        }
        if (lane == 0) { redv[wv] = v; redi[wv] = ix; } }
      __syncthreads();
      if (tid < 2) {
        float v = redv[tid * 8]; int ix = redi[tid * 8];
        for (int i = 1; i < 8; ++i) {
          float vi = redv[tid * 8 + i]; int ii2 = redi[tid * 8 + i];
          if (vi > v || (vi == v && ii2 < ix)) { v = vi; ix = ii2; }
        }
        s_zmax[tid] = v; s_ns[tid] = ix;
        float x = cohl(&hcat[(size_t)(b0 + tid) * WC + COL_TAU]) + b_h2tau[0];
        s_tau[tid] = fmaxf(x, 0.0f) + log1pf(expf(-fabsf(x))) + 1.0f;
      }
      __syncthreads();
      { float e = expf((zg - s_zmax[bq]) / s_tau[bq]);
        for (int off = 32; off; off >>= 1) e += __shfl_down(e, off, 64);
        if (lane == 0) redv[wv] = e; }
      __syncthreads();
      if (tid < 2) {
        float D = 0;
        for (int i = 0; i < 8; ++i) D += redv[tid * 8 + i];
        float ystar = 1.0f / D;
        s_ws[tid] = (1.0f - ystar) + ystar;
      }
      __syncthreads();
      if (tid < 512) {     // r gather
        int bq2 = tid >> 8, m = tid & 255;
        int ns = s_ns[bq2], sW = sm.o.lwL[bq2][ns];
        float mv = (m < AA) ? mem_bias[(size_t)ns * AC + m]
                 : ((sW >= 0) ? valHistG[((size_t)(b0 + bq2) * LL + sW) * CCd + m - AA] : 0.0f);
        sm.o.rsL[bq2][m] = s_ws[bq2] * mv;
      }
      __syncthreads();
      if (tid < 2) {       // bookkeeping after r-gather
        int ns = s_ns[tid];
        int pos = (t < 16) ? t * LL : ns;
        sm.o.wpL[tid][t] = pos;
        sm.o.lwL[tid][pos] = t;
        sm.o.wsL[tid][ns] += s_ws[tid];
      }
      if (wv < 10) {       // 10 wave-jobs: {gate0..2, ab0..1} x 2 batches
        int gb = wv & 1, jj = wv >> 1;
        float p = 0;
        if (jj < 3) {
#pragma unroll
          for (int k = lane; k < ID; k += 64) p = fmaf(sm.o.embL[gb][k], Wi2g[k * 3 + jj], p);
#pragma unroll
          for (int k = lane; k < AC; k += 64) p = fmaf(sm.o.rsL[gb][k], Wr2g[k * 3 + jj], p);
        } else {
          int j = jj - 3;
#pragma unroll
          for (int k = lane; k < ID; k += 64) p = fmaf(sm.o.embL[gb][k], Wi2ab[k * 2 + j], p);
#pragma unroll
          for (int k = lane; k < AC; k += 64) p = fmaf(sm.o.rsL[gb][k], Wr2ab[k * 2 + j], p);
        }
        for (int off = 32; off; off >>= 1) p += __shfl_down(p, off, 64);
        if (lane == 0) {
          if (jj < 3) {
            float x = p + cohl(&hcat[(size_t)(b0 + gb) * WC + COL_G0 + jj]);
            s_fio[gb][jj] = 1.0f / (1.0f + expf(-x));
          } else {
            int j = jj - 3;
            float x = p + cohl(&hcat[(size_t)(b0 + gb) * WC + COL_AB0 + j]);
            uint32_t i1 = (uint32_t)((((size_t)t * BB + b0 + gb) * 2 + j) * 2);
            uint32_t o0, o1;
            threefry2x32(k2a, k2b, 0u, i1, o0, o1);     float g1 = bits_to_gumbel(o0 ^ o1);
            threefry2x32(k2a, k2b, 0u, i1 + 1, o0, o1); float g2 = bits_to_gumbel(o0 ^ o1);
            s_ab[gb][j] = (x + g1 - g2) > 0.0f ? 1.0f : 0.0f;
          }
        }
      }
      __syncthreads();
      {  // LSTM update: thread = col c (0..1023), both batches share Wr2c load
        const int c = tid;
        float rc0 = 0, rc1 = 0;
        if (s_ab[0][0] != 0.0f || s_ab[1][0] != 0.0f) {
          const float* wp = Wr2c + c;
#pragma unroll 16
          for (int k = 0; k < AC; ++k) {
            float w = wp[(size_t)k * HD];
            rc0 = fmaf(sm.o.rsL[0][k], w, rc0);
            rc1 = fmaf(sm.o.rsL[1][k], w, rc1);
          }
        }
#pragma unroll
        for (int q = 0; q < 2; ++q) {
          const float alpha = s_ab[q][0], beta = s_ab[q][1];
          const float fg = s_fio[q][0], ig = s_fio[q][1], og = s_fio[q][2];
          const size_t row = (size_t)t * BB + b0 + q;
          float hc = (beta != 0.0f) ? cohl(&hcat[(size_t)(b0 + q) * WC + c]) : 0.0f;
          float arg = beta * hc + icatC[row * HD + c] + alpha * (q ? rc1 : rc0);
          float cn = fg * sm.o.ccL[q][c] + ig * tanhf(arg);
          float hn = og * tanhf(cn);
          sm.o.ccL[q][c] = cn;
          sm.o.hL[q][c] = hn;
          out[row * HD + c] = hn;
          if (t + 1 < LL) cohs(&hbuf[(size_t)(b0 + q) * HD + c], hn);
        }
      }
    }
    if (t + 1 < LL) gbar(bar_cnt, bar_flag, epoch);
  }
}

// ------------------------------ host ---------------------------------------
extern "C" void kernel_launch(void* const* d_in, const int* in_sizes, int n_in,
                              void* d_out, int out_size, void* d_ws, size_t ws_size,
                              hipStream_t stream) {
  const float* inp      = (const float*)d_in[0];
  const float* hid      = (const float*)d_in[1];
  const float* mem_bias = (const float*)d_in[2];
  const float* W_h2w    = (const float*)d_in[3];
  const float* W_i2w    = (const float*)d_in[4];
  const float* W_m2w    = (const float*)d_in[5];
  const float* W_u2w    = (const float*)d_in[6];
  const float* W_h2g    = (const float*)d_in[7];
  const float* W_i2g    = (const float*)d_in[8];
  const float* W_r2g    = (const float*)d_in[9];
  const float* W_h2ab   = (const float*)d_in[10];
  const float* W_i2ab   = (const float*)d_in[11];
  const float* W_r2ab   = (const float*)d_in[12];
  const float* W_h2c    = (const float*)d_in[13];
  const float* W_i2c    = (const float*)d_in[14];
  const float* W_r2c    = (const float*)d_in[15];
  const float* atten    = (const float*)d_in[16];
  const float* W_h2tau  = (const float*)d_in[17];
  const float* b_h2tau  = (const float*)d_in[18];
  const float* W_h2m    = (const float*)d_in[19];
  float* out = (float*)d_out;

  char* base = (char*)d_ws;
  size_t off = 0;
  auto alloc = [&](size_t elems) -> void* {
    void* p = (void*)(base + off);
    off += ((elems * 4 + 255) / 256) * 256;
    return p;
  };
  float* icatC  = (float*)alloc((size_t)LL * BB * HD);
  float* icatW  = (float*)alloc((size_t)LL * BB * AC);
  float* Wcat   = (float*)alloc((size_t)HD * WC);
  float* addrW  = (float*)alloc((size_t)NS * AC);
  float* addrWT = (float*)alloc((size_t)NS * AC);
  float* hbuf   = (float*)alloc((size_t)BB * HD);
  float* hcat   = (float*)alloc((size_t)BB * WC);
  float* valHistG  = (float*)alloc((size_t)BB * LL * CCd);
  float* valWHistG = (float*)alloc((size_t)BB * LL * AC);
  unsigned int* bar = (unsigned int*)alloc(512);   // [0]=counter, [256]=flag

  hipLaunchKernelGGL(pack_wcat, dim3((HD * WC + 255) / 256), dim3(256), 0, stream,
                     W_h2c, W_h2w, W_h2g, W_h2ab, W_h2tau, Wcat);
  hipLaunchKernelGGL(addrw_kernel, dim3((NS * AC + 255) / 256), dim3(256), 0, stream,
                     mem_bias, W_m2w, addrW, addrWT);
  hipLaunchKernelGGL(init_kernel, dim3((BB * HD + 255) / 256), dim3(256), 0, stream,
                     hid, hbuf, bar);
  hipLaunchKernelGGL(gemm_big, dim3((LL * BB) / 128, HD / 64), dim3(256), 0, stream,
                     inp, W_i2c, icatC, ID, HD);
  hipLaunchKernelGGL(gemm_big, dim3((LL * BB) / 128, AC / 64), dim3(256), 0, stream,
                     inp, W_i2w, icatW, ID, AC);
  hipLaunchKernelGGL(persist_kernel, dim3(GRID_P), dim3(1024), 0, stream,
                     inp, hid, mem_bias, icatC, icatW, Wcat, addrW, addrWT, atten,
                     W_i2g, W_r2g, W_i2ab, W_r2ab, W_r2c, b_h2tau,
                     W_h2m, W_m2w, W_u2w,
                     hbuf, hcat, valHistG, valWHistG, bar, bar + 256, out);
}

// Round 10
// 4991.479 us; speedup vs baseline: 1.2933x; 1.2933x over previous
//
#include <hip/hip_runtime.h>
#include <hip/hip_bf16.h>
#include <math.h>

// ---------------------------------------------------------------------------
// DecoderTARDIS forward, fp32 — v8 = R8 structure + contention-free barrier.
// R9 lesson: 2-batch owners regressed (FETCH 3.5x) -> reverted to R8.
// R10 change (ONLY): barrier arrival was a serialized fetch_add chain through
// one LLC line (~50us/barrier for 240 blocks). Now: per-block arrival SLOT
// (128B stride, plain agent store, parallel), master block polls slots with
// 240 threads, single release flag. Expected ~2-4us/barrier.
// ---------------------------------------------------------------------------

static constexpr int LL   = 32;
static constexpr int BB   = 128;
static constexpr int ID   = 512;
static constexpr int HD   = 1024;
static constexpr int NS   = 512;
static constexpr int AA   = 128;
static constexpr int CCd  = 128;
static constexpr int AC   = 256;
static constexpr int WC   = 1344;           // 112 * 12
static constexpr int COL_W0  = 1024;
static constexpr int COL_G0  = 1280;
static constexpr int COL_AB0 = 1283;
static constexpr int COL_TAU = 1285;
static constexpr int NOWN = 128;
static constexpr int NAB  = 112;
static constexpr int GRID_P = NOWN + NAB;   // 240
static constexpr int FSTRIDE = 32;          // words (128 B) per arrival slot

// ------------------------------ threefry -----------------------------------
__device__ __forceinline__ uint32_t rotl32(uint32_t x, uint32_t r) {
  return (x << r) | (x >> (32u - r));
}

__device__ __forceinline__ void threefry2x32(uint32_t k0, uint32_t k1,
                                             uint32_t x0, uint32_t x1,
                                             uint32_t& o0, uint32_t& o1) {
  uint32_t ks0 = k0, ks1 = k1, ks2 = 0x1BD11BDAu ^ k0 ^ k1;
  x0 += ks0; x1 += ks1;
#define TFR(r) { x0 += x1; x1 = rotl32(x1, r); x1 ^= x0; }
  TFR(13u) TFR(15u) TFR(26u) TFR(6u)   x0 += ks1; x1 += ks2 + 1u;
  TFR(17u) TFR(29u) TFR(16u) TFR(24u)  x0 += ks2; x1 += ks0 + 2u;
  TFR(13u) TFR(15u) TFR(26u) TFR(6u)   x0 += ks0; x1 += ks1 + 3u;
  TFR(17u) TFR(29u) TFR(16u) TFR(24u)  x0 += ks1; x1 += ks2 + 4u;
  TFR(13u) TFR(15u) TFR(26u) TFR(6u)   x0 += ks2; x1 += ks0 + 5u;
#undef TFR
  o0 = x0; o1 = x1;
}

__device__ __forceinline__ float bits_to_gumbel(uint32_t bits) {
  uint32_t v = (bits >> 9) | 0x3F800000u;
  float f = __uint_as_float(v) - 1.0f;
  if (f <= 0.0f) f = 1.17549435e-38f;
  return -logf(-logf(f));
}

__device__ __forceinline__ float fast_tanh(float x) {
  float e = __expf(2.0f * x);
  return 1.0f - 2.0f / (e + 1.0f);
}

// --------------- coherent (agent-scope, relaxed) access helpers ------------
__device__ __forceinline__ float cohl(const float* p) {
  return __hip_atomic_load(p, __ATOMIC_RELAXED, __HIP_MEMORY_SCOPE_AGENT);
}
__device__ __forceinline__ void cohs(float* p, float v) {
  __hip_atomic_store(p, v, __ATOMIC_RELAXED, __HIP_MEMORY_SCOPE_AGENT);
}
__device__ __forceinline__ float2 cohl2(const float* p) {
  unsigned long long u = __hip_atomic_load((const unsigned long long*)p,
                                           __ATOMIC_RELAXED, __HIP_MEMORY_SCOPE_AGENT);
  float2 r; __builtin_memcpy(&r, &u, 8); return r;
}
__device__ __forceinline__ void cohs2(float* p, float2 v) {
  unsigned long long u; __builtin_memcpy(&u, &v, 8);
  __hip_atomic_store((unsigned long long*)p, u, __ATOMIC_RELAXED, __HIP_MEMORY_SCOPE_AGENT);
}

// ------- grid barrier: parallel per-block arrival slots + master poll ------
__device__ __forceinline__ void gbar(unsigned int* arrive, unsigned int* flag,
                                     unsigned int& epoch, int blk) {
  asm volatile("s_waitcnt vmcnt(0)" ::: "memory");
  __syncthreads();
  epoch++;
  if (blk == 0) {
    int i = threadIdx.x;
    if (i > 0 && i < GRID_P) {
      while (__hip_atomic_load(&arrive[i * FSTRIDE], __ATOMIC_RELAXED,
                               __HIP_MEMORY_SCOPE_AGENT) < epoch) {
        __builtin_amdgcn_s_sleep(2);
      }
    }
    __syncthreads();
    if (threadIdx.x == 0)
      __hip_atomic_store(flag, epoch, __ATOMIC_RELAXED, __HIP_MEMORY_SCOPE_AGENT);
  } else {
    if (threadIdx.x == 0) {
      __hip_atomic_store(&arrive[blk * FSTRIDE], epoch, __ATOMIC_RELAXED,
                         __HIP_MEMORY_SCOPE_AGENT);
      while (__hip_atomic_load(flag, __ATOMIC_RELAXED,
                               __HIP_MEMORY_SCOPE_AGENT) < epoch) {
        __builtin_amdgcn_s_sleep(2);
      }
    }
  }
  __syncthreads();
}

// ------------------------------ prologue -----------------------------------
__global__ void pack_wcat(const float* __restrict__ Wh2c, const float* __restrict__ Wh2w,
                          const float* __restrict__ Wh2g, const float* __restrict__ Wh2ab,
                          const float* __restrict__ Wh2tau, float* __restrict__ Wcat) {
  int idx = blockIdx.x * blockDim.x + threadIdx.x;
  if (idx >= HD * WC) return;
  int k = idx / WC, c = idx % WC;
  float v = 0.0f;
  if (c < 1024)       v = Wh2c[(size_t)k * HD + c];
  else if (c < 1280)  v = Wh2w[(size_t)k * AC + (c - 1024)];
  else if (c < 1283)  v = Wh2g[k * 3 + (c - 1280)];
  else if (c < 1285)  v = Wh2ab[k * 2 + (c - 1283)];
  else if (c == 1285) v = Wh2tau[k];
  Wcat[idx] = v;
}

__global__ void addrw_kernel(const float* __restrict__ mem_bias,
                             const float* __restrict__ Wm2w,
                             float* __restrict__ addrW, float* __restrict__ addrWT) {
  int idx = blockIdx.x * blockDim.x + threadIdx.x;
  if (idx >= NS * AC) return;
  int n = idx / AC, m = idx % AC;
  float acc = 0.0f;
  for (int k = 0; k < AA; k++) acc += mem_bias[(size_t)n * AC + k] * Wm2w[(size_t)k * AC + m];
  addrW[(size_t)n * AC + m] = acc;
  addrWT[(size_t)m * NS + n] = acc;
}

__global__ void init_kernel(const float* __restrict__ hid, float* __restrict__ hbuf,
                            unsigned int* __restrict__ bar) {
  int idx = blockIdx.x * blockDim.x + threadIdx.x;
  if (idx < BB * HD) hbuf[idx] = hid[idx];
  if (idx < 9216) bar[idx] = 0u;   // arrival slots + flag line
}

// generic fp32 GEMM: C(M x Nw) = A(M x K) @ W(K x Nw); 128x64 tile, 8x4/thr
__global__ __launch_bounds__(256) void gemm_big(const float* __restrict__ A,
                                                const float* __restrict__ W,
                                                float* __restrict__ C,
                                                int K, int Nw) {
  __shared__ float sA[32][132];
  __shared__ float sB[32][68];
  const int tx = threadIdx.x & 15, ty = threadIdx.x >> 4;
  const int m0 = blockIdx.x * 128, n0 = blockIdx.y * 64;
  float acc[8][4] = {};
  for (int k0 = 0; k0 < K; k0 += 32) {
    for (int i = threadIdx.x; i < 128 * 32; i += 256) {
      int r = i >> 5, kk = i & 31;
      sA[kk][r] = A[(size_t)(m0 + r) * K + k0 + kk];
    }
    for (int i = threadIdx.x; i < 32 * 64; i += 256) {
      int kk = i >> 6, c = i & 63;
      sB[kk][c] = W[(size_t)(k0 + kk) * Nw + n0 + c];
    }
    __syncthreads();
#pragma unroll
    for (int kk = 0; kk < 32; ++kk) {
      float4 a0 = *(const float4*)&sA[kk][ty * 8];
      float4 a1 = *(const float4*)&sA[kk][ty * 8 + 4];
      float4 b0 = *(const float4*)&sB[kk][tx * 4];
      float ar[8] = {a0.x, a0.y, a0.z, a0.w, a1.x, a1.y, a1.z, a1.w};
      float br[4] = {b0.x, b0.y, b0.z, b0.w};
#pragma unroll
      for (int i2 = 0; i2 < 8; ++i2)
#pragma unroll
        for (int j2 = 0; j2 < 4; ++j2)
          acc[i2][j2] = fmaf(ar[i2], br[j2], acc[i2][j2]);
    }
    __syncthreads();
  }
#pragma unroll
  for (int i2 = 0; i2 < 8; ++i2) {
    float4 st = make_float4(acc[i2][0], acc[i2][1], acc[i2][2], acc[i2][3]);
    *(float4*)&C[(size_t)(m0 + ty * 8 + i2) * Nw + n0 + tx * 4] = st;
  }
}

// ------------------------------ persistent kernel --------------------------
struct AS { float w[12][1032]; float hst[128][68]; };   // 49.5 + 34.8 KB
struct OS {
  float hL[HD]; float ccL[HD];
  float embL[ID];
  float w_sumL[NS]; float zl[NS];
  float u2wL[AC]; float biasL[AC]; float attL[AC]; float rsL[AC];
  float valHistL[LL][CCd];
  float valWHistL[LL][AC];
  float scratch[512];
  int   lastWriterL[NS];
  int   writePosL[LL];
};
union SU { AS a; OS o; };

__global__ __launch_bounds__(512) void persist_kernel(
    const float* __restrict__ inp, const float* __restrict__ hid,
    const float* __restrict__ mem_bias,
    const float* __restrict__ icatC, const float* __restrict__ icatW,
    const float* __restrict__ Wcat,
    const float* __restrict__ addrW, const float* __restrict__ addrWT,
    const float* __restrict__ atten,
    const float* __restrict__ Wi2g, const float* __restrict__ Wr2g,
    const float* __restrict__ Wi2ab, const float* __restrict__ Wr2ab,
    const float* __restrict__ Wr2c,
    const float* __restrict__ b_h2tau,
    const float* __restrict__ Wh2m, const float* __restrict__ Wm2w,
    const float* __restrict__ Wu2w,
    float* hbuf, float* hcat,
    unsigned int* bar_arrive, unsigned int* bar_flag,
    float* __restrict__ out) {
  const int blk = blockIdx.x, tid = threadIdx.x;
  const int lane = tid & 63, wv = tid >> 6;
  __shared__ SU sm;
  __shared__ float redv[8]; __shared__ int redi[8];
  __shared__ float s_fio[3], s_ab[2], s_tau, s_zmax, s_ws; __shared__ int s_ns;
  unsigned int epoch = 0;

  uint32_t k1a, k1b, k2a, k2b;
  threefry2x32(0u, 42u, 0u, 0u, k1a, k1b);
  threefry2x32(0u, 42u, 0u, 1u, k2a, k2b);

  const bool owner = (blk < NOWN);
  const int b = blk;                 // owner's batch
  const int an0 = (blk - NOWN) * 12; // A-block's first col

  if (owner) {
    for (int i = tid; i < HD; i += 512) {
      sm.o.hL[i] = hid[(size_t)b * HD + i];
      sm.o.ccL[i] = 0.0f;
    }
    if (tid < NS) { sm.o.w_sumL[tid] = 0.0f; sm.o.lastWriterL[tid] = -1; }
    if (tid < AC) { sm.o.attL[tid] = atten[tid]; sm.o.u2wL[tid] = 0.0f; }
  } else {
    // one-time: this block's 12 Wcat cols -> LDS
    for (int i = tid; i < 12 * 1024; i += 512) {
      int k = i / 12, c = i - k * 12;
      sm.a.w[c][k] = Wcat[(size_t)k * WC + an0 + c];
    }
  }
  __syncthreads();

  for (int t = 0; t < LL; ++t) {
    const size_t row = (size_t)t * BB + b;
    // =================== window A ======================================
    if (!owner) {
      const int cg = tid & 3, rowg = tid >> 2;   // compute threads: tid<128
      float acc[4][3] = {};
      float2 pre[8];
#pragma unroll
      for (int ii = 0; ii < 8; ++ii) {           // prefetch chunk 0
        int f = ii * 512 + tid, r2 = f >> 5, k2 = f & 31;
        pre[ii] = cohl2(&hbuf[(size_t)r2 * HD + k2 * 2]);
      }
      for (int kc = 0; kc < HD; kc += 64) {
        __syncthreads();
#pragma unroll
        for (int ii = 0; ii < 8; ++ii) {
          int f = ii * 512 + tid, r2 = f >> 5, k2 = f & 31;
          *(float2*)&sm.a.hst[r2][k2 * 2] = pre[ii];
        }
        __syncthreads();
        if (kc + 64 < HD) {
#pragma unroll
          for (int ii = 0; ii < 8; ++ii) {
            int f = ii * 512 + tid, r2 = f >> 5, k2 = f & 31;
            pre[ii] = cohl2(&hbuf[(size_t)r2 * HD + kc + 64 + k2 * 2]);
          }
        }
        if (tid < 128) {
#pragma unroll
          for (int k4 = 0; k4 < 16; ++k4) {
            float4 w0 = *(const float4*)&sm.a.w[cg * 3 + 0][kc + k4 * 4];
            float4 w1 = *(const float4*)&sm.a.w[cg * 3 + 1][kc + k4 * 4];
            float4 w2 = *(const float4*)&sm.a.w[cg * 3 + 2][kc + k4 * 4];
#pragma unroll
            for (int j = 0; j < 4; ++j) {
              float4 h4 = *(const float4*)&sm.a.hst[rowg + 32 * j][k4 * 4];
              acc[j][0] = fmaf(h4.x, w0.x, fmaf(h4.y, w0.y, fmaf(h4.z, w0.z, fmaf(h4.w, w0.w, acc[j][0]))));
              acc[j][1] = fmaf(h4.x, w1.x, fmaf(h4.y, w1.y, fmaf(h4.z, w1.z, fmaf(h4.w, w1.w, acc[j][1]))));
              acc[j][2] = fmaf(h4.x, w2.x, fmaf(h4.y, w2.y, fmaf(h4.z, w2.z, fmaf(h4.w, w2.w, acc[j][2]))));
            }
          }
        }
      }
      if (tid < 128) {
#pragma unroll
        for (int j = 0; j < 4; ++j)
#pragma unroll
          for (int c = 0; c < 3; ++c)
            cohs(&hcat[(size_t)(rowg + 32 * j) * WC + an0 + cg * 3 + c], acc[j][c]);
      }
    } else {
      // owner A-window: emb load, val/valW for t-1, u2w for t (own LDS state)
      if (tid < ID) sm.o.embL[tid] = inp[row * ID + tid];
      if (t > 0) {
        { int c = tid & 127, q = tid >> 7; float a3 = 0; int k0 = q * 256;
#pragma unroll 4
          for (int k = k0; k < k0 + 256; ++k) a3 = fmaf(sm.o.hL[k], Wh2m[(size_t)k * CCd + c], a3);
          sm.o.scratch[tid] = a3; }
        __syncthreads();
        if (tid < CCd)
          sm.o.valHistL[t - 1][tid] = sm.o.scratch[tid] + sm.o.scratch[tid + 128] +
                                      sm.o.scratch[tid + 256] + sm.o.scratch[tid + 384];
        __syncthreads();
        { int m = tid & 255, q = tid >> 8; float a3 = 0; int c0 = q * 64;
#pragma unroll 4
          for (int c = c0; c < c0 + 64; ++c)
            a3 = fmaf(sm.o.valHistL[t - 1][c], Wm2w[(size_t)(AA + c) * AC + m], a3);
          sm.o.scratch[tid] = a3; }
        __syncthreads();
        if (tid < AC) sm.o.valWHistL[t - 1][tid] = sm.o.scratch[tid] + sm.o.scratch[tid + 256];
        __syncthreads();
      }
      // u2w = LayerNorm(w_sum) @ Wu2w
      {
        float v = sm.o.w_sumL[tid];       // tid < 512 == NS
        float s1 = v;
        for (int off = 32; off; off >>= 1) s1 += __shfl_down(s1, off, 64);
        if (lane == 0) redv[wv] = s1;
        __syncthreads();
        float mu = 0; for (int i = 0; i < 8; ++i) mu += redv[i]; mu /= (float)NS;
        __syncthreads();
        float d = (v - mu) * (v - mu);
        for (int off = 32; off; off >>= 1) d += __shfl_down(d, off, 64);
        if (lane == 0) redv[wv] = d;
        __syncthreads();
        float var = 0; for (int i = 0; i < 8; ++i) var += redv[i]; var /= (float)NS;
        float rsq = rsqrtf(var + 1e-5f);
        sm.o.zl[tid] = (v - mu) * rsq;
        __syncthreads();
        { int m = tid & 255, q = tid >> 8; float a3 = 0; int k0 = q * 256;
#pragma unroll 4
          for (int k = k0; k < k0 + 256; ++k) a3 = fmaf(sm.o.zl[k], Wu2w[(size_t)k * AC + m], a3);
          sm.o.scratch[tid] = a3; }
        __syncthreads();
        if (tid < AC) sm.o.u2wL[tid] = sm.o.scratch[tid] + sm.o.scratch[tid + 256];
      }
    }
    gbar(bar_arrive, bar_flag, epoch, blk);

    // =================== window LS (owners) ============================
    if (owner) {
      if (tid < AC)
        sm.o.biasL[tid] = cohl(&hcat[(size_t)b * WC + COL_W0 + tid]) +
                          icatW[row * AC + tid] + sm.o.u2wL[tid];
      __syncthreads();
      {  // logits, n = tid
        float p = 0.0f;
        const float* awc = addrWT + tid;
#pragma unroll 8
        for (int k = 0; k < AC; ++k)
          p = fmaf(fast_tanh(sm.o.biasL[k] + awc[(size_t)k * NS]), sm.o.attL[k], p);
        sm.o.zl[tid] = p;
      }
      __syncthreads();
      for (int j = wv; j < t; j += 8) {   // corrections for written slots
        int n2 = sm.o.writePosL[j];
        int s = sm.o.lastWriterL[n2];
        float q = 0.0f;
        for (int k = lane; k < AC; k += 64)
          q = fmaf(fast_tanh(sm.o.biasL[k] + addrW[(size_t)n2 * AC + k] + sm.o.valWHistL[s][k]),
                   sm.o.attL[k], q);
        for (int off = 32; off; off >>= 1) q += __shfl_down(q, off, 64);
        if (lane == 0) sm.o.zl[n2] = q;
      }
      __syncthreads();
      float zg;
      {
        uint32_t gi = (uint32_t)(row * NS + tid);
        uint32_t o0, o1; threefry2x32(k1a, k1b, 0u, gi, o0, o1);
        zg = sm.o.zl[tid] + bits_to_gumbel(o0 ^ o1);
      }
      { float v = zg; int ix = tid;
        for (int off = 32; off; off >>= 1) {
          float vo = __shfl_down(v, off, 64); int io = __shfl_down(ix, off, 64);
          if (vo > v || (vo == v && io < ix)) { v = vo; ix = io; }
        }
        if (lane == 0) { redv[wv] = v; redi[wv] = ix; } }
      __syncthreads();
      if (tid == 0) {
        float v = redv[0]; int ix = redi[0];
        for (int i = 1; i < 8; ++i)
          if (redv[i] > v || (redv[i] == v && redi[i] < ix)) { v = redv[i]; ix = redi[i]; }
        s_zmax = v; s_ns = ix;
        float x = cohl(&hcat[(size_t)b * WC + COL_TAU]) + b_h2tau[0];
        s_tau = fmaxf(x, 0.0f) + log1pf(expf(-fabsf(x))) + 1.0f;
      }
      __syncthreads();
      { float e = expf((zg - s_zmax) / s_tau);
        for (int off = 32; off; off >>= 1) e += __shfl_down(e, off, 64);
        if (lane == 0) redv[wv] = e; }
      __syncthreads();
      if (tid == 0) {
        float D = 0; for (int i = 0; i < 8; ++i) D += redv[i];
        float ystar = 1.0f / D;
        s_ws = (1.0f - ystar) + ystar;
      }
      __syncthreads();
      const int ns = s_ns; const float ws = s_ws;
      if (tid < AC) {
        int sW = sm.o.lastWriterL[ns];
        float mv = (tid < AA) ? mem_bias[(size_t)ns * AC + tid]
                 : ((sW >= 0) ? sm.o.valHistL[sW][tid - AA] : 0.0f);
        sm.o.rsL[tid] = ws * mv;
      }
      __syncthreads();
      // bookkeeping (wave 0 lane 0) || gates (waves 1-3) || ab (waves 4-5)
      if (tid == 0) {
        int pos = (t < 16) ? t * LL : ns;
        sm.o.writePosL[t] = pos;
        sm.o.lastWriterL[pos] = t;
        sm.o.w_sumL[ns] += ws;
      }
      if (wv >= 1 && wv <= 3) {
        int j = wv - 1; float p = 0.0f;
        for (int k = lane; k < ID; k += 64) p = fmaf(sm.o.embL[k], Wi2g[k * 3 + j], p);
        for (int k = lane; k < AC; k += 64) p = fmaf(sm.o.rsL[k], Wr2g[k * 3 + j], p);
        for (int off = 32; off; off >>= 1) p += __shfl_down(p, off, 64);
        if (lane == 0) {
          float x = p + cohl(&hcat[(size_t)b * WC + COL_G0 + j]);
          s_fio[j] = 1.0f / (1.0f + expf(-x));
        }
      } else if (wv >= 4 && wv <= 5) {
        int j = wv - 4; float p = 0.0f;
        for (int k = lane; k < ID; k += 64) p = fmaf(sm.o.embL[k], Wi2ab[k * 2 + j], p);
        for (int k = lane; k < AC; k += 64) p = fmaf(sm.o.rsL[k], Wr2ab[k * 2 + j], p);
        for (int off = 32; off; off >>= 1) p += __shfl_down(p, off, 64);
        if (lane == 0) {
          float x = p + cohl(&hcat[(size_t)b * WC + COL_AB0 + j]);
          uint32_t i1 = (uint32_t)((row * 2 + j) * 2);
          uint32_t o0, o1;
          threefry2x32(k2a, k2b, 0u, i1, o0, o1);     float g1 = bits_to_gumbel(o0 ^ o1);
          threefry2x32(k2a, k2b, 0u, i1 + 1, o0, o1); float g2 = bits_to_gumbel(o0 ^ o1);
          s_ab[j] = (x + g1 - g2) > 0.0f ? 1.0f : 0.0f;
        }
      }
      __syncthreads();
      const float fg = s_fio[0], ig = s_fio[1], og = s_fio[2];
      const float alpha = s_ab[0], beta = s_ab[1];
      const int c0 = tid * 2;
      {
        float rc0 = 0.0f, rc1 = 0.0f;
        if (alpha != 0.0f) {
#pragma unroll 4
          for (int k = 0; k < AC; ++k) {
            float rk = sm.o.rsL[k];
            float2 w2 = *(const float2*)&Wr2c[(size_t)k * HD + c0];
            rc0 = fmaf(rk, w2.x, rc0); rc1 = fmaf(rk, w2.y, rc1);
          }
        }
        float2 hc2 = (beta != 0.0f) ? cohl2(&hcat[(size_t)b * WC + c0]) : make_float2(0.f, 0.f);
        float2 ic2 = *(const float2*)&icatC[row * HD + c0];
        float a0 = beta * hc2.x + ic2.x + alpha * rc0;
        float a1 = beta * hc2.y + ic2.y + alpha * rc1;
        float cn0 = fg * sm.o.ccL[c0] + ig * tanhf(a0);
        float cn1 = fg * sm.o.ccL[c0 + 1] + ig * tanhf(a1);
        float hn0 = og * tanhf(cn0), hn1 = og * tanhf(cn1);
        sm.o.ccL[c0] = cn0; sm.o.ccL[c0 + 1] = cn1;
        sm.o.hL[c0] = hn0; sm.o.hL[c0 + 1] = hn1;
        *(float2*)&out[row * HD + c0] = make_float2(hn0, hn1);
        if (t + 1 < LL) cohs2(&hbuf[(size_t)b * HD + c0], make_float2(hn0, hn1));
      }
      __syncthreads();
    }
    if (t + 1 < LL) gbar(bar_arrive, bar_flag, epoch, blk);
  }
}

// ------------------------------ host ---------------------------------------
extern "C" void kernel_launch(void* const* d_in, const int* in_sizes, int n_in,
                              void* d_out, int out_size, void* d_ws, size_t ws_size,
                              hipStream_t stream) {
  const float* inp      = (const float*)d_in[0];
  const float* hid      = (const float*)d_in[1];
  const float* mem_bias = (const float*)d_in[2];
  const float* W_h2w    = (const float*)d_in[3];
  const float* W_i2w    = (const float*)d_in[4];
  const float* W_m2w    = (const float*)d_in[5];
  const float* W_u2w    = (const float*)d_in[6];
  const float* W_h2g    = (const float*)d_in[7];
  const float* W_i2g    = (const float*)d_in[8];
  const float* W_r2g    = (const float*)d_in[9];
  const float* W_h2ab   = (const float*)d_in[10];
  const float* W_i2ab   = (const float*)d_in[11];
  const float* W_r2ab   = (const float*)d_in[12];
  const float* W_h2c    = (const float*)d_in[13];
  const float* W_i2c    = (const float*)d_in[14];
  const float* W_r2c    = (const float*)d_in[15];
  const float* atten    = (const float*)d_in[16];
  const float* W_h2tau  = (const float*)d_in[17];
  const float* b_h2tau  = (const float*)d_in[18];
  const float* W_h2m    = (const float*)d_in[19];
  float* out = (float*)d_out;

  char* base = (char*)d_ws;
  size_t off = 0;
  auto alloc = [&](size_t elems) -> void* {
    void* p = (void*)(base + off);
    off += ((elems * 4 + 255) / 256) * 256;
    return p;
  };
  float* icatC  = (float*)alloc((size_t)LL * BB * HD);   // inp @ W_i2c
  float* icatW  = (float*)alloc((size_t)LL * BB * AC);   // inp @ W_i2w
  float* Wcat   = (float*)alloc((size_t)HD * WC);
  float* addrW  = (float*)alloc((size_t)NS * AC);
  float* addrWT = (float*)alloc((size_t)NS * AC);
  float* hbuf   = (float*)alloc((size_t)BB * HD);
  float* hcat   = (float*)alloc((size_t)BB * WC);
  unsigned int* bar = (unsigned int*)alloc(9216);  // [0..7679]=slots, [8192]=flag

  hipLaunchKernelGGL(pack_wcat, dim3((HD * WC + 255) / 256), dim3(256), 0, stream,
                     W_h2c, W_h2w, W_h2g, W_h2ab, W_h2tau, Wcat);
  hipLaunchKernelGGL(addrw_kernel, dim3((NS * AC + 255) / 256), dim3(256), 0, stream,
                     mem_bias, W_m2w, addrW, addrWT);
  hipLaunchKernelGGL(init_kernel, dim3((BB * HD + 255) / 256), dim3(256), 0, stream,
                     hid, hbuf, bar);
  hipLaunchKernelGGL(gemm_big, dim3((LL * BB) / 128, HD / 64), dim3(256), 0, stream,
                     inp, W_i2c, icatC, ID, HD);
  hipLaunchKernelGGL(gemm_big, dim3((LL * BB) / 128, AC / 64), dim3(256), 0, stream,
                     inp, W_i2w, icatW, ID, AC);
  hipLaunchKernelGGL(persist_kernel, dim3(GRID_P), dim3(512), 0, stream,
                     inp, hid, mem_bias, icatC, icatW, Wcat, addrW, addrWT, atten,
                     W_i2g, W_r2g, W_i2ab, W_r2ab, W_r2c, b_h2tau,
                     W_h2m, W_m2w, W_u2w,
                     hbuf, hcat, bar, bar + 8192, out);
}

// Round 11
// 4629.995 us; speedup vs baseline: 1.3943x; 1.0781x over previous
//
#include <hip/hip_runtime.h>
#include <hip/hip_bf16.h>
#include <math.h>

// ---------------------------------------------------------------------------
// DecoderTARDIS forward, fp32 — v9: R8/R10 skeleton, latency-focused fixes.
// R10 lesson: barriers exonerated (slot barrier = no change). FETCH 8MB/step
// = streamed weights re-fetched past L2 every step; owner GEMVs run at LLC
// latency with shallow MLP. v9: 1024 threads/block (4 waves/SIMD), deep
// unroll + split accumulators (16 loads in flight), non-temporal loads for
// single-use streams (icatC/icatW/inp/out) to keep weights L2-resident.
// ---------------------------------------------------------------------------

static constexpr int LL   = 32;
static constexpr int BB   = 128;
static constexpr int ID   = 512;
static constexpr int HD   = 1024;
static constexpr int NS   = 512;
static constexpr int AA   = 128;
static constexpr int CCd  = 128;
static constexpr int AC   = 256;
static constexpr int WC   = 1344;           // 112 * 12
static constexpr int COL_W0  = 1024;
static constexpr int COL_G0  = 1280;
static constexpr int COL_AB0 = 1283;
static constexpr int COL_TAU = 1285;
static constexpr int NOWN = 128;
static constexpr int NAB  = 112;
static constexpr int GRID_P = NOWN + NAB;   // 240
static constexpr int FSTRIDE = 32;          // words (128 B) per arrival slot

// ------------------------------ threefry -----------------------------------
__device__ __forceinline__ uint32_t rotl32(uint32_t x, uint32_t r) {
  return (x << r) | (x >> (32u - r));
}

__device__ __forceinline__ void threefry2x32(uint32_t k0, uint32_t k1,
                                             uint32_t x0, uint32_t x1,
                                             uint32_t& o0, uint32_t& o1) {
  uint32_t ks0 = k0, ks1 = k1, ks2 = 0x1BD11BDAu ^ k0 ^ k1;
  x0 += ks0; x1 += ks1;
#define TFR(r) { x0 += x1; x1 = rotl32(x1, r); x1 ^= x0; }
  TFR(13u) TFR(15u) TFR(26u) TFR(6u)   x0 += ks1; x1 += ks2 + 1u;
  TFR(17u) TFR(29u) TFR(16u) TFR(24u)  x0 += ks2; x1 += ks0 + 2u;
  TFR(13u) TFR(15u) TFR(26u) TFR(6u)   x0 += ks0; x1 += ks1 + 3u;
  TFR(17u) TFR(29u) TFR(16u) TFR(24u)  x0 += ks1; x1 += ks2 + 4u;
  TFR(13u) TFR(15u) TFR(26u) TFR(6u)   x0 += ks2; x1 += ks0 + 5u;
#undef TFR
  o0 = x0; o1 = x1;
}

__device__ __forceinline__ float bits_to_gumbel(uint32_t bits) {
  uint32_t v = (bits >> 9) | 0x3F800000u;
  float f = __uint_as_float(v) - 1.0f;
  if (f <= 0.0f) f = 1.17549435e-38f;
  return -logf(-logf(f));
}

__device__ __forceinline__ float fast_tanh(float x) {
  float e = __expf(2.0f * x);
  return 1.0f - 2.0f / (e + 1.0f);
}

// --------------- coherent (agent-scope, relaxed) access helpers ------------
__device__ __forceinline__ float cohl(const float* p) {
  return __hip_atomic_load(p, __ATOMIC_RELAXED, __HIP_MEMORY_SCOPE_AGENT);
}
__device__ __forceinline__ void cohs(float* p, float v) {
  __hip_atomic_store(p, v, __ATOMIC_RELAXED, __HIP_MEMORY_SCOPE_AGENT);
}
__device__ __forceinline__ float2 cohl2(const float* p) {
  unsigned long long u = __hip_atomic_load((const unsigned long long*)p,
                                           __ATOMIC_RELAXED, __HIP_MEMORY_SCOPE_AGENT);
  float2 r; __builtin_memcpy(&r, &u, 8); return r;
}

// ------- grid barrier: parallel per-block arrival slots + master poll ------
__device__ __forceinline__ void gbar(unsigned int* arrive, unsigned int* flag,
                                     unsigned int& epoch, int blk) {
  asm volatile("s_waitcnt vmcnt(0)" ::: "memory");
  __syncthreads();
  epoch++;
  if (blk == 0) {
    int i = threadIdx.x;
    if (i > 0 && i < GRID_P) {
      while (__hip_atomic_load(&arrive[i * FSTRIDE], __ATOMIC_RELAXED,
                               __HIP_MEMORY_SCOPE_AGENT) < epoch) {
        __builtin_amdgcn_s_sleep(2);
      }
    }
    __syncthreads();
    if (threadIdx.x == 0)
      __hip_atomic_store(flag, epoch, __ATOMIC_RELAXED, __HIP_MEMORY_SCOPE_AGENT);
  } else {
    if (threadIdx.x == 0) {
      __hip_atomic_store(&arrive[blk * FSTRIDE], epoch, __ATOMIC_RELAXED,
                         __HIP_MEMORY_SCOPE_AGENT);
      while (__hip_atomic_load(flag, __ATOMIC_RELAXED,
                               __HIP_MEMORY_SCOPE_AGENT) < epoch) {
        __builtin_amdgcn_s_sleep(2);
      }
    }
  }
  __syncthreads();
}

// ------------------------------ prologue -----------------------------------
__global__ void pack_wcat(const float* __restrict__ Wh2c, const float* __restrict__ Wh2w,
                          const float* __restrict__ Wh2g, const float* __restrict__ Wh2ab,
                          const float* __restrict__ Wh2tau, float* __restrict__ Wcat) {
  int idx = blockIdx.x * blockDim.x + threadIdx.x;
  if (idx >= HD * WC) return;
  int k = idx / WC, c = idx % WC;
  float v = 0.0f;
  if (c < 1024)       v = Wh2c[(size_t)k * HD + c];
  else if (c < 1280)  v = Wh2w[(size_t)k * AC + (c - 1024)];
  else if (c < 1283)  v = Wh2g[k * 3 + (c - 1280)];
  else if (c < 1285)  v = Wh2ab[k * 2 + (c - 1283)];
  else if (c == 1285) v = Wh2tau[k];
  Wcat[idx] = v;
}

__global__ void addrw_kernel(const float* __restrict__ mem_bias,
                             const float* __restrict__ Wm2w,
                             float* __restrict__ addrW, float* __restrict__ addrWT) {
  int idx = blockIdx.x * blockDim.x + threadIdx.x;
  if (idx >= NS * AC) return;
  int n = idx / AC, m = idx % AC;
  float acc = 0.0f;
  for (int k = 0; k < AA; k++) acc += mem_bias[(size_t)n * AC + k] * Wm2w[(size_t)k * AC + m];
  addrW[(size_t)n * AC + m] = acc;
  addrWT[(size_t)m * NS + n] = acc;
}

__global__ void init_kernel(const float* __restrict__ hid, float* __restrict__ hbuf,
                            unsigned int* __restrict__ bar) {
  int idx = blockIdx.x * blockDim.x + threadIdx.x;
  if (idx < BB * HD) hbuf[idx] = hid[idx];
  if (idx < 9216) bar[idx] = 0u;   // arrival slots + flag line
}

// generic fp32 GEMM: C(M x Nw) = A(M x K) @ W(K x Nw); 128x64 tile, 8x4/thr
__global__ __launch_bounds__(256) void gemm_big(const float* __restrict__ A,
                                                const float* __restrict__ W,
                                                float* __restrict__ C,
                                                int K, int Nw) {
  __shared__ float sA[32][132];
  __shared__ float sB[32][68];
  const int tx = threadIdx.x & 15, ty = threadIdx.x >> 4;
  const int m0 = blockIdx.x * 128, n0 = blockIdx.y * 64;
  float acc[8][4] = {};
  for (int k0 = 0; k0 < K; k0 += 32) {
    for (int i = threadIdx.x; i < 128 * 32; i += 256) {
      int r = i >> 5, kk = i & 31;
      sA[kk][r] = A[(size_t)(m0 + r) * K + k0 + kk];
    }
    for (int i = threadIdx.x; i < 32 * 64; i += 256) {
      int kk = i >> 6, c = i & 63;
      sB[kk][c] = W[(size_t)(k0 + kk) * Nw + n0 + c];
    }
    __syncthreads();
#pragma unroll
    for (int kk = 0; kk < 32; ++kk) {
      float4 a0 = *(const float4*)&sA[kk][ty * 8];
      float4 a1 = *(const float4*)&sA[kk][ty * 8 + 4];
      float4 b0 = *(const float4*)&sB[kk][tx * 4];
      float ar[8] = {a0.x, a0.y, a0.z, a0.w, a1.x, a1.y, a1.z, a1.w};
      float br[4] = {b0.x, b0.y, b0.z, b0.w};
#pragma unroll
      for (int i2 = 0; i2 < 8; ++i2)
#pragma unroll
        for (int j2 = 0; j2 < 4; ++j2)
          acc[i2][j2] = fmaf(ar[i2], br[j2], acc[i2][j2]);
    }
    __syncthreads();
  }
#pragma unroll
  for (int i2 = 0; i2 < 8; ++i2) {
    float4 st = make_float4(acc[i2][0], acc[i2][1], acc[i2][2], acc[i2][3]);
    *(float4*)&C[(size_t)(m0 + ty * 8 + i2) * Nw + n0 + tx * 4] = st;
  }
}

// ------------------------------ persistent kernel --------------------------
struct AS { float w[12][1032]; float hst[128][68]; };   // 49.5 + 34.8 KB
struct OS {
  float hL[HD]; float ccL[HD];
  float embL[ID];
  float w_sumL[NS]; float zl[NS];
  float u2wL[AC]; float biasL[AC]; float attL[AC]; float rsL[AC];
  float valHistL[LL][CCd];
  float valWHistL[LL][AC];
  float scratch[1024];
  int   lastWriterL[NS];
  int   writePosL[LL];
};
union SU { AS a; OS o; };

__global__ __launch_bounds__(1024) void persist_kernel(
    const float* __restrict__ inp, const float* __restrict__ hid,
    const float* __restrict__ mem_bias,
    const float* __restrict__ icatC, const float* __restrict__ icatW,
    const float* __restrict__ Wcat,
    const float* __restrict__ addrW, const float* __restrict__ addrWT,
    const float* __restrict__ atten,
    const float* __restrict__ Wi2g, const float* __restrict__ Wr2g,
    const float* __restrict__ Wi2ab, const float* __restrict__ Wr2ab,
    const float* __restrict__ Wr2c,
    const float* __restrict__ b_h2tau,
    const float* __restrict__ Wh2m, const float* __restrict__ Wm2w,
    const float* __restrict__ Wu2w,
    float* hbuf, float* hcat,
    unsigned int* bar_arrive, unsigned int* bar_flag,
    float* __restrict__ out) {
  const int blk = blockIdx.x, tid = threadIdx.x;
  const int lane = tid & 63, wv = tid >> 6;        // 16 waves
  __shared__ SU sm;
  __shared__ float redv[16]; __shared__ int redi[16];
  __shared__ float s_fio[3], s_ab[2], s_tau, s_zmax, s_ws; __shared__ int s_ns;
  unsigned int epoch = 0;

  uint32_t k1a, k1b, k2a, k2b;
  threefry2x32(0u, 42u, 0u, 0u, k1a, k1b);
  threefry2x32(0u, 42u, 0u, 1u, k2a, k2b);

  const bool owner = (blk < NOWN);
  const int b = blk;                 // owner's batch
  const int an0 = (blk - NOWN) * 12; // A-block's first col

  if (owner) {
    sm.o.hL[tid] = hid[(size_t)b * HD + tid];
    sm.o.ccL[tid] = 0.0f;
    if (tid < NS) { sm.o.w_sumL[tid] = 0.0f; sm.o.lastWriterL[tid] = -1; }
    if (tid < AC) { sm.o.attL[tid] = atten[tid]; sm.o.u2wL[tid] = 0.0f; }
  } else {
    for (int i = tid; i < 12 * 1024; i += 1024) {
      int k = i / 12, c = i - k * 12;
      sm.a.w[c][k] = Wcat[(size_t)k * WC + an0 + c];
    }
  }
  __syncthreads();

  for (int t = 0; t < LL; ++t) {
    const size_t row = (size_t)t * BB + b;
    // =================== window A ======================================
    if (!owner) {
      const int cg = tid & 3, rg = tid >> 2;       // compute threads: tid<256
      float acc[2][3] = {};
      float2 pre[4];
#pragma unroll
      for (int ii = 0; ii < 4; ++ii) {             // prefetch chunk 0
        int f = ii * 1024 + tid, r2 = f >> 5, k2 = f & 31;
        pre[ii] = cohl2(&hbuf[(size_t)r2 * HD + k2 * 2]);
      }
      for (int kc = 0; kc < HD; kc += 64) {
        __syncthreads();
#pragma unroll
        for (int ii = 0; ii < 4; ++ii) {
          int f = ii * 1024 + tid, r2 = f >> 5, k2 = f & 31;
          *(float2*)&sm.a.hst[r2][k2 * 2] = pre[ii];
        }
        __syncthreads();
        if (kc + 64 < HD) {
#pragma unroll
          for (int ii = 0; ii < 4; ++ii) {
            int f = ii * 1024 + tid, r2 = f >> 5, k2 = f & 31;
            pre[ii] = cohl2(&hbuf[(size_t)r2 * HD + kc + 64 + k2 * 2]);
          }
        }
        if (tid < 256) {
#pragma unroll
          for (int k4 = 0; k4 < 16; ++k4) {
            float4 w0 = *(const float4*)&sm.a.w[cg * 3 + 0][kc + k4 * 4];
            float4 w1 = *(const float4*)&sm.a.w[cg * 3 + 1][kc + k4 * 4];
            float4 w2 = *(const float4*)&sm.a.w[cg * 3 + 2][kc + k4 * 4];
#pragma unroll
            for (int j = 0; j < 2; ++j) {
              float4 h4 = *(const float4*)&sm.a.hst[rg + 64 * j][k4 * 4];
              acc[j][0] = fmaf(h4.x, w0.x, fmaf(h4.y, w0.y, fmaf(h4.z, w0.z, fmaf(h4.w, w0.w, acc[j][0]))));
              acc[j][1] = fmaf(h4.x, w1.x, fmaf(h4.y, w1.y, fmaf(h4.z, w1.z, fmaf(h4.w, w1.w, acc[j][1]))));
              acc[j][2] = fmaf(h4.x, w2.x, fmaf(h4.y, w2.y, fmaf(h4.z, w2.z, fmaf(h4.w, w2.w, acc[j][2]))));
            }
          }
        }
      }
      if (tid < 256) {
#pragma unroll
        for (int j = 0; j < 2; ++j)
#pragma unroll
          for (int c = 0; c < 3; ++c)
            cohs(&hcat[(size_t)(rg + 64 * j) * WC + an0 + cg * 3 + c], acc[j][c]);
      }
    } else {
      // owner A-window: emb, val/valW(t-1), u2w(t), all from own LDS state
      if (tid < ID) sm.o.embL[tid] = __builtin_nontemporal_load(&inp[row * ID + tid]);
      if (t > 0) {
        { int c = tid & 127, q = tid >> 7;          // 8 k-groups of 128
          float a0 = 0, a1 = 0; int k0 = q * 128;
#pragma unroll 8
          for (int k = k0; k < k0 + 128; k += 2) {
            a0 = fmaf(sm.o.hL[k],     Wh2m[(size_t)k * CCd + c],       a0);
            a1 = fmaf(sm.o.hL[k + 1], Wh2m[(size_t)(k + 1) * CCd + c], a1);
          }
          sm.o.scratch[tid] = a0 + a1; }
        __syncthreads();
        if (tid < CCd) {
          float v = 0;
#pragma unroll
          for (int i = 0; i < 8; ++i) v += sm.o.scratch[i * 128 + tid];
          sm.o.valHistL[t - 1][tid] = v;
        }
        __syncthreads();
        { int m = tid & 255, q = tid >> 8;          // 4 c-groups of 32
          float a0 = 0; int c0 = q * 32;
#pragma unroll 8
          for (int c = c0; c < c0 + 32; ++c)
            a0 = fmaf(sm.o.valHistL[t - 1][c], Wm2w[(size_t)(AA + c) * AC + m], a0);
          sm.o.scratch[q * 256 + m] = a0; }
        __syncthreads();
        if (tid < AC)
          sm.o.valWHistL[t - 1][tid] = sm.o.scratch[tid] + sm.o.scratch[tid + 256] +
                                       sm.o.scratch[tid + 512] + sm.o.scratch[tid + 768];
        __syncthreads();
      }
      // u2w = LayerNorm(w_sum) @ Wu2w
      {
        float v = (tid < NS) ? sm.o.w_sumL[tid] : 0.0f;
        float s1 = v;
        for (int off = 32; off; off >>= 1) s1 += __shfl_down(s1, off, 64);
        if (lane == 0) redv[wv] = s1;
        __syncthreads();
        float mu = 0;
#pragma unroll
        for (int i = 0; i < 16; ++i) mu += redv[i];
        mu /= (float)NS;
        __syncthreads();
        float d = (tid < NS) ? (v - mu) * (v - mu) : 0.0f;
        for (int off = 32; off; off >>= 1) d += __shfl_down(d, off, 64);
        if (lane == 0) redv[wv] = d;
        __syncthreads();
        float var = 0;
#pragma unroll
        for (int i = 0; i < 16; ++i) var += redv[i];
        var /= (float)NS;
        float rsq = rsqrtf(var + 1e-5f);
        if (tid < NS) sm.o.zl[tid] = (v - mu) * rsq;
        __syncthreads();
        { int m = tid & 255, q = tid >> 8;          // 4 k-groups of 128
          float a0 = 0, a1 = 0; int k0 = q * 128;
#pragma unroll 8
          for (int k = k0; k < k0 + 128; k += 2) {
            a0 = fmaf(sm.o.zl[k],     Wu2w[(size_t)k * AC + m],       a0);
            a1 = fmaf(sm.o.zl[k + 1], Wu2w[(size_t)(k + 1) * AC + m], a1);
          }
          sm.o.scratch[q * 256 + m] = a0 + a1; }
        __syncthreads();
        if (tid < AC)
          sm.o.u2wL[tid] = sm.o.scratch[tid] + sm.o.scratch[tid + 256] +
                           sm.o.scratch[tid + 512] + sm.o.scratch[tid + 768];
      }
    }
    gbar(bar_arrive, bar_flag, epoch, blk);

    // =================== window LS (owners) ============================
    if (owner) {
      if (tid < AC)
        sm.o.biasL[tid] = cohl(&hcat[(size_t)b * WC + COL_W0 + tid]) +
                          __builtin_nontemporal_load(&icatW[row * AC + tid]) +
                          sm.o.u2wL[tid];
      __syncthreads();
      {  // logits: n = tid&511, kh = tid>>9 splits K in halves
        int n = tid & 511, kh = tid >> 9;
        float p = 0.0f; int k0 = kh * 128;
        const float* awc = addrWT + n;
#pragma unroll 8
        for (int k = k0; k < k0 + 128; ++k)
          p = fmaf(fast_tanh(sm.o.biasL[k] + awc[(size_t)k * NS]), sm.o.attL[k], p);
        sm.o.scratch[kh * 512 + n] = p;
      }
      __syncthreads();
      if (tid < NS) sm.o.zl[tid] = sm.o.scratch[tid] + sm.o.scratch[tid + 512];
      __syncthreads();
      for (int j = wv; j < t; j += 16) {   // corrections for written slots
        int n2 = sm.o.writePosL[j];
        int s = sm.o.lastWriterL[n2];
        float q = 0.0f;
        for (int k = lane; k < AC; k += 64)
          q = fmaf(fast_tanh(sm.o.biasL[k] + addrW[(size_t)n2 * AC + k] + sm.o.valWHistL[s][k]),
                   sm.o.attL[k], q);
        for (int off = 32; off; off >>= 1) q += __shfl_down(q, off, 64);
        if (lane == 0) sm.o.zl[n2] = q;
      }
      __syncthreads();
      float zg = -1e30f;
      if (tid < NS) {
        uint32_t gi = (uint32_t)(row * NS + tid);
        uint32_t o0, o1; threefry2x32(k1a, k1b, 0u, gi, o0, o1);
        zg = sm.o.zl[tid] + bits_to_gumbel(o0 ^ o1);
      }
      { float v = zg; int ix = (tid < NS) ? tid : 0x7fffffff;
        for (int off = 32; off; off >>= 1) {
          float vo = __shfl_down(v, off, 64); int io = __shfl_down(ix, off, 64);
          if (vo > v || (vo == v && io < ix)) { v = vo; ix = io; }
        }
        if (lane == 0) { redv[wv] = v; redi[wv] = ix; } }
      __syncthreads();
      if (tid == 0) {
        float v = redv[0]; int ix = redi[0];
        for (int i = 1; i < 8; ++i)
          if (redv[i] > v || (redv[i] == v && redi[i] < ix)) { v = redv[i]; ix = redi[i]; }
        s_zmax = v; s_ns = ix;
        float x = cohl(&hcat[(size_t)b * WC + COL_TAU]) + b_h2tau[0];
        s_tau = fmaxf(x, 0.0f) + log1pf(expf(-fabsf(x))) + 1.0f;
      }
      __syncthreads();
      { float e = (tid < NS) ? expf((zg - s_zmax) / s_tau) : 0.0f;
        for (int off = 32; off; off >>= 1) e += __shfl_down(e, off, 64);
        if (lane == 0) redv[wv] = e; }
      __syncthreads();
      if (tid == 0) {
        float D = 0;
        for (int i = 0; i < 8; ++i) D += redv[i];
        float ystar = 1.0f / D;
        s_ws = (1.0f - ystar) + ystar;
      }
      __syncthreads();
      const int ns = s_ns; const float ws = s_ws;
      if (tid < AC) {
        int sW = sm.o.lastWriterL[ns];
        float mv = (tid < AA) ? mem_bias[(size_t)ns * AC + tid]
                 : ((sW >= 0) ? sm.o.valHistL[sW][tid - AA] : 0.0f);
        sm.o.rsL[tid] = ws * mv;
      }
      __syncthreads();
      // bookkeeping (lane 0) || gates (waves 1-3) || ab (waves 4-5)
      if (tid == 0) {
        int pos = (t < 16) ? t * LL : ns;
        sm.o.writePosL[t] = pos;
        sm.o.lastWriterL[pos] = t;
        sm.o.w_sumL[ns] += ws;
      }
      if (wv >= 1 && wv <= 3) {
        int j = wv - 1; float p = 0.0f;
        for (int k = lane; k < ID; k += 64) p = fmaf(sm.o.embL[k], Wi2g[k * 3 + j], p);
        for (int k = lane; k < AC; k += 64) p = fmaf(sm.o.rsL[k], Wr2g[k * 3 + j], p);
        for (int off = 32; off; off >>= 1) p += __shfl_down(p, off, 64);
        if (lane == 0) {
          float x = p + cohl(&hcat[(size_t)b * WC + COL_G0 + j]);
          s_fio[j] = 1.0f / (1.0f + expf(-x));
        }
      } else if (wv >= 4 && wv <= 5) {
        int j = wv - 4; float p = 0.0f;
        for (int k = lane; k < ID; k += 64) p = fmaf(sm.o.embL[k], Wi2ab[k * 2 + j], p);
        for (int k = lane; k < AC; k += 64) p = fmaf(sm.o.rsL[k], Wr2ab[k * 2 + j], p);
        for (int off = 32; off; off >>= 1) p += __shfl_down(p, off, 64);
        if (lane == 0) {
          float x = p + cohl(&hcat[(size_t)b * WC + COL_AB0 + j]);
          uint32_t i1 = (uint32_t)((row * 2 + j) * 2);
          uint32_t o0, o1;
          threefry2x32(k2a, k2b, 0u, i1, o0, o1);     float g1 = bits_to_gumbel(o0 ^ o1);
          threefry2x32(k2a, k2b, 0u, i1 + 1, o0, o1); float g2 = bits_to_gumbel(o0 ^ o1);
          s_ab[j] = (x + g1 - g2) > 0.0f ? 1.0f : 0.0f;
        }
      }
      __syncthreads();
      const float fg = s_fio[0], ig = s_fio[1], og = s_fio[2];
      const float alpha = s_ab[0], beta = s_ab[1];
      {  // LSTM update: thread c = tid (1024 cols), 16 loads in flight
        const int c = tid;
        float rc = 0.0f;
        if (alpha != 0.0f) {
          const float* wp = Wr2c + c;
          float a0 = 0, a1 = 0, a2 = 0, a3 = 0;
#pragma unroll 4
          for (int k = 0; k < AC; k += 4) {
            a0 = fmaf(sm.o.rsL[k + 0], wp[(size_t)(k + 0) * HD], a0);
            a1 = fmaf(sm.o.rsL[k + 1], wp[(size_t)(k + 1) * HD], a1);
            a2 = fmaf(sm.o.rsL[k + 2], wp[(size_t)(k + 2) * HD], a2);
            a3 = fmaf(sm.o.rsL[k + 3], wp[(size_t)(k + 3) * HD], a3);
          }
          rc = (a0 + a1) + (a2 + a3);
        }
        float hc = (beta != 0.0f) ? cohl(&hcat[(size_t)b * WC + c]) : 0.0f;
        float ic = __builtin_nontemporal_load(&icatC[row * HD + c]);
        float arg = beta * hc + ic + alpha * rc;
        float cn = fg * sm.o.ccL[c] + ig * tanhf(arg);
        float hn = og * tanhf(cn);
        sm.o.ccL[c] = cn;
        sm.o.hL[c] = hn;
        __builtin_nontemporal_store(hn, &out[row * HD + c]);
        if (t + 1 < LL) cohs(&hbuf[(size_t)b * HD + c], hn);
      }
      __syncthreads();
    }
    if (t + 1 < LL) gbar(bar_arrive, bar_flag, epoch, blk);
  }
}

// ------------------------------ host ---------------------------------------
extern "C" void kernel_launch(void* const* d_in, const int* in_sizes, int n_in,
                              void* d_out, int out_size, void* d_ws, size_t ws_size,
                              hipStream_t stream) {
  const float* inp      = (const float*)d_in[0];
  const float* hid      = (const float*)d_in[1];
  const float* mem_bias = (const float*)d_in[2];
  const float* W_h2w    = (const float*)d_in[3];
  const float* W_i2w    = (const float*)d_in[4];
  const float* W_m2w    = (const float*)d_in[5];
  const float* W_u2w    = (const float*)d_in[6];
  const float* W_h2g    = (const float*)d_in[7];
  const float* W_i2g    = (const float*)d_in[8];
  const float* W_r2g    = (const float*)d_in[9];
  const float* W_h2ab   = (const float*)d_in[10];
  const float* W_i2ab   = (const float*)d_in[11];
  const float* W_r2ab   = (const float*)d_in[12];
  const float* W_h2c    = (const float*)d_in[13];
  const float* W_i2c    = (const float*)d_in[14];
  const float* W_r2c    = (const float*)d_in[15];
  const float* atten    = (const float*)d_in[16];
  const float* W_h2tau  = (const float*)d_in[17];
  const float* b_h2tau  = (const float*)d_in[18];
  const float* W_h2m    = (const float*)d_in[19];
  float* out = (float*)d_out;

  char* base = (char*)d_ws;
  size_t off = 0;
  auto alloc = [&](size_t elems) -> void* {
    void* p = (void*)(base + off);
    off += ((elems * 4 + 255) / 256) * 256;
    return p;
  };
  float* icatC  = (float*)alloc((size_t)LL * BB * HD);   // inp @ W_i2c
  float* icatW  = (float*)alloc((size_t)LL * BB * AC);   // inp @ W_i2w
  float* Wcat   = (float*)alloc((size_t)HD * WC);
  float* addrW  = (float*)alloc((size_t)NS * AC);
  float* addrWT = (float*)alloc((size_t)NS * AC);
  float* hbuf   = (float*)alloc((size_t)BB * HD);
  float* hcat   = (float*)alloc((size_t)BB * WC);
  unsigned int* bar = (unsigned int*)alloc(9216);  // [0..7679]=slots, [8192]=flag

  hipLaunchKernelGGL(pack_wcat, dim3((HD * WC + 255) / 256), dim3(256), 0, stream,
                     W_h2c, W_h2w, W_h2g, W_h2ab, W_h2tau, Wcat);
  hipLaunchKernelGGL(addrw_kernel, dim3((NS * AC + 255) / 256), dim3(256), 0, stream,
                     mem_bias, W_m2w, addrW, addrWT);
  hipLaunchKernelGGL(init_kernel, dim3((BB * HD + 255) / 256), dim3(256), 0, stream,
                     hid, hbuf, bar);
  hipLaunchKernelGGL(gemm_big, dim3((LL * BB) / 128, HD / 64), dim3(256), 0, stream,
                     inp, W_i2c, icatC, ID, HD);
  hipLaunchKernelGGL(gemm_big, dim3((LL * BB) / 128, AC / 64), dim3(256), 0, stream,
                     inp, W_i2w, icatW, ID, AC);
  hipLaunchKernelGGL(persist_kernel, dim3(GRID_P), dim3(1024), 0, stream,
                     inp, hid, mem_bias, icatC, icatW, Wcat, addrW, addrWT, atten,
                     W_i2g, W_r2g, W_i2ab, W_r2ab, W_r2c, b_h2tau,
                     W_h2m, W_m2w, W_u2w,
                     hbuf, hcat, bar, bar + 8192, out);
}

// Round 12
// 4368.111 us; speedup vs baseline: 1.4779x; 1.0600x over previous
//
#include <hip/hip_runtime.h>
#include <hip/hip_bf16.h>
#include <math.h>

// ---------------------------------------------------------------------------
// DecoderTARDIS forward, fp32 — v10: back to launch-per-phase (R1 structure),
// redesigned for full-GPU parallel phases + L2 weight reuse.
// R11 lesson: persistent kernel is unmeasurable (one opaque dispatch) and
// three independent levers failed to move time. Launch boundaries = sync,
// each phase rocprof-visible. 4 launches/step:
//   K1: hcat GEMM (336 blk) || val GEMM (16) || u2w GEMM (32)
//   K2: logits tanh + on-the-fly corrections + gumbel + chunk argmax (512)
//   K3: select/denom/r/gates/ab/bookkeeping (128)
//   K4: LSTM update with Wr2c col-chunks (512) || LayerNorm(w_sum) (128)
// valWHist eliminated: corrections recompute val@Wm2w on the fly (L2-hot).
// ---------------------------------------------------------------------------

static constexpr int LL   = 32;
static constexpr int BB   = 128;
static constexpr int ID   = 512;
static constexpr int HD   = 1024;
static constexpr int NS   = 512;
static constexpr int AA   = 128;
static constexpr int CCd  = 128;
static constexpr int AC   = 256;
static constexpr int WC   = 1344;
static constexpr int COL_W0  = 1024;
static constexpr int COL_G0  = 1280;
static constexpr int COL_TAU = 1285;

// ------------------------------ threefry -----------------------------------
__device__ __forceinline__ uint32_t rotl32(uint32_t x, uint32_t r) {
  return (x << r) | (x >> (32u - r));
}

__device__ __forceinline__ void threefry2x32(uint32_t k0, uint32_t k1,
                                             uint32_t x0, uint32_t x1,
                                             uint32_t& o0, uint32_t& o1) {
  uint32_t ks0 = k0, ks1 = k1, ks2 = 0x1BD11BDAu ^ k0 ^ k1;
  x0 += ks0; x1 += ks1;
#define TFR(r) { x0 += x1; x1 = rotl32(x1, r); x1 ^= x0; }
  TFR(13u) TFR(15u) TFR(26u) TFR(6u)   x0 += ks1; x1 += ks2 + 1u;
  TFR(17u) TFR(29u) TFR(16u) TFR(24u)  x0 += ks2; x1 += ks0 + 2u;
  TFR(13u) TFR(15u) TFR(26u) TFR(6u)   x0 += ks0; x1 += ks1 + 3u;
  TFR(17u) TFR(29u) TFR(16u) TFR(24u)  x0 += ks1; x1 += ks2 + 4u;
  TFR(13u) TFR(15u) TFR(26u) TFR(6u)   x0 += ks2; x1 += ks0 + 5u;
#undef TFR
  o0 = x0; o1 = x1;
}

__device__ __forceinline__ float bits_to_gumbel(uint32_t bits) {
  uint32_t v = (bits >> 9) | 0x3F800000u;
  float f = __uint_as_float(v) - 1.0f;
  if (f <= 0.0f) f = 1.17549435e-38f;
  return -logf(-logf(f));
}

__device__ __forceinline__ float fast_tanh(float x) {
  float e = __expf(2.0f * x);
  return 1.0f - 2.0f / (e + 1.0f);
}

// ------------------------------ prologue -----------------------------------
__global__ void pack_wcat(const float* __restrict__ Wh2c, const float* __restrict__ Wh2w,
                          const float* __restrict__ Wh2g, const float* __restrict__ Wh2ab,
                          const float* __restrict__ Wh2tau, float* __restrict__ Wcat) {
  int idx = blockIdx.x * blockDim.x + threadIdx.x;
  if (idx >= HD * WC) return;
  int k = idx / WC, c = idx % WC;
  float v = 0.0f;
  if (c < 1024)       v = Wh2c[(size_t)k * HD + c];
  else if (c < 1280)  v = Wh2w[(size_t)k * AC + (c - 1024)];
  else if (c < 1283)  v = Wh2g[k * 3 + (c - 1280)];
  else if (c < 1285)  v = Wh2ab[k * 2 + (c - 1283)];
  else if (c == 1285) v = Wh2tau[k];
  Wcat[idx] = v;
}

__global__ void addrw_kernel(const float* __restrict__ mem_bias,
                             const float* __restrict__ Wm2w,
                             float* __restrict__ addrW, float* __restrict__ addrWT) {
  int idx = blockIdx.x * blockDim.x + threadIdx.x;
  if (idx >= NS * AC) return;
  int n = idx / AC, m = idx % AC;
  float acc = 0.0f;
  for (int k = 0; k < AA; k++) acc += mem_bias[(size_t)n * AC + k] * Wm2w[(size_t)k * AC + m];
  addrW[(size_t)n * AC + m] = acc;
  addrWT[(size_t)m * NS + n] = acc;
}

// emb @ [Wi2g | Wi2ab]  -> icatG[row][5]
__global__ void icatg_kernel(const float* __restrict__ inp,
                             const float* __restrict__ Wi2g,
                             const float* __restrict__ Wi2ab,
                             float* __restrict__ icatG) {
  int idx = blockIdx.x * blockDim.x + threadIdx.x;
  if (idx >= LL * BB * 5) return;
  int row = idx / 5, j = idx % 5;
  const float* a = inp + (size_t)row * ID;
  float acc = 0.0f;
  if (j < 3) { for (int k = 0; k < ID; ++k) acc = fmaf(a[k], Wi2g[k * 3 + j], acc); }
  else { int jj = j - 3; for (int k = 0; k < ID; ++k) acc = fmaf(a[k], Wi2ab[k * 2 + jj], acc); }
  icatG[row * 5 + j] = acc;
}

__global__ void init_kernel(const float* __restrict__ hid, float* __restrict__ hbuf,
                            float* __restrict__ ccbuf, float* __restrict__ w_sum,
                            float* __restrict__ zlbuf, int* __restrict__ lastWriter) {
  int idx = blockIdx.x * blockDim.x + threadIdx.x;
  if (idx < BB * HD) { hbuf[idx] = hid[idx]; ccbuf[idx] = 0.0f; }
  if (idx < BB * NS) { w_sum[idx] = 0.0f; zlbuf[idx] = 0.0f; lastWriter[idx] = -1; }
}

// generic fp32 GEMM: C(M x Nw) = A(M x K) @ W(K x Nw); 128x64 tile, 8x4/thr
__global__ __launch_bounds__(256) void gemm_big(const float* __restrict__ A,
                                                const float* __restrict__ W,
                                                float* __restrict__ C,
                                                int K, int Nw) {
  __shared__ float sA[32][132];
  __shared__ float sB[32][68];
  const int tx = threadIdx.x & 15, ty = threadIdx.x >> 4;
  const int m0 = blockIdx.x * 128, n0 = blockIdx.y * 64;
  float acc[8][4] = {};
  for (int k0 = 0; k0 < K; k0 += 32) {
    for (int i = threadIdx.x; i < 128 * 32; i += 256) {
      int r = i >> 5, kk = i & 31;
      sA[kk][r] = A[(size_t)(m0 + r) * K + k0 + kk];
    }
    for (int i = threadIdx.x; i < 32 * 64; i += 256) {
      int kk = i >> 6, c = i & 63;
      sB[kk][c] = W[(size_t)(k0 + kk) * Nw + n0 + c];
    }
    __syncthreads();
#pragma unroll
    for (int kk = 0; kk < 32; ++kk) {
      float4 a0 = *(const float4*)&sA[kk][ty * 8];
      float4 a1 = *(const float4*)&sA[kk][ty * 8 + 4];
      float4 b0 = *(const float4*)&sB[kk][tx * 4];
      float ar[8] = {a0.x, a0.y, a0.z, a0.w, a1.x, a1.y, a1.z, a1.w};
      float br[4] = {b0.x, b0.y, b0.z, b0.w};
#pragma unroll
      for (int i2 = 0; i2 < 8; ++i2)
#pragma unroll
        for (int j2 = 0; j2 < 4; ++j2)
          acc[i2][j2] = fmaf(ar[i2], br[j2], acc[i2][j2]);
    }
    __syncthreads();
  }
#pragma unroll
  for (int i2 = 0; i2 < 8; ++i2) {
    float4 st = make_float4(acc[i2][0], acc[i2][1], acc[i2][2], acc[i2][3]);
    *(float4*)&C[(size_t)(m0 + ty * 8 + i2) * Nw + n0 + tx * 4] = st;
  }
}

// 32x32 output tile GEMM helper (256 threads), K in chunks of 64
__device__ void tile_gemm32(const float* __restrict__ A, int lda,
                            const float* __restrict__ W, int ldw,
                            float* __restrict__ C, int ldc,
                            int m0, int n0, int kbase, int klen) {
  __shared__ float sAT[64][36];
  __shared__ float sW[64][33];
  const int col = threadIdx.x & 31, rg = threadIdx.x >> 5;
  float acc[4] = {0.0f, 0.0f, 0.0f, 0.0f};
  for (int k0 = kbase; k0 < kbase + klen; k0 += 64) {
    for (int i = threadIdx.x; i < 32 * 64; i += 256) {
      int r = i >> 6, kk = i & 63;
      sAT[kk][r] = A[(size_t)(m0 + r) * lda + k0 + kk];
    }
    for (int i = threadIdx.x; i < 64 * 32; i += 256) {
      int kk = i >> 5, c = i & 31;
      sW[kk][c] = W[(size_t)(k0 + kk) * ldw + n0 + c];
    }
    __syncthreads();
#pragma unroll 8
    for (int kk = 0; kk < 64; ++kk) {
      float4 a = *(const float4*)&sAT[kk][rg * 4];
      float w = sW[kk][col];
      acc[0] = fmaf(a.x, w, acc[0]); acc[1] = fmaf(a.y, w, acc[1]);
      acc[2] = fmaf(a.z, w, acc[2]); acc[3] = fmaf(a.w, w, acc[3]);
    }
    __syncthreads();
  }
#pragma unroll
  for (int j = 0; j < 4; ++j)
    C[(size_t)(m0 + rg * 4 + j) * ldc + n0 + col] = acc[j];
}

// ------------------- K1: hcat partials || val || u2w -----------------------
__global__ __launch_bounds__(256) void k1_pre(
    const float* __restrict__ hbuf, const float* __restrict__ Wcat,
    const float* __restrict__ Wh2m, const float* __restrict__ zlbuf,
    const float* __restrict__ Wu2w,
    float* __restrict__ hcp, float* __restrict__ valHist,
    float* __restrict__ u2wbuf, int t) {
  const int blk = blockIdx.x;
  if (blk < 336) {                       // hcat = h @ Wcat, 2-way split-K
    int tile = blk >> 1, part = blk & 1;
    int m0 = (tile & 3) * 32, n0 = (tile >> 2) * 32;
    tile_gemm32(hbuf, HD, Wcat, WC, hcp + (size_t)part * BB * WC, WC,
                m0, n0, part * 512, 512);
  } else if (blk < 352) {                // val(t-1) = h @ Wh2m
    if (t == 0) return;
    int b2 = blk - 336;
    int m0 = (b2 & 3) * 32, n0 = (b2 >> 2) * 32;
    tile_gemm32(hbuf, HD, Wh2m, CCd, valHist + (size_t)(t - 1) * CCd, LL * CCd,
                m0, n0, 0, HD);
  } else if (blk < 384) {                // u2w = zl @ Wu2w
    int b3 = blk - 352;
    int m0 = (b3 & 3) * 32, n0 = (b3 >> 2) * 32;
    tile_gemm32(zlbuf, NS, Wu2w, AC, u2wbuf, AC, m0, n0, 0, NS);
  }
}

// ------------------- K2: logits + corrections + gumbel + argmax ------------
__global__ __launch_bounds__(256) void k2_logits(
    const float* __restrict__ hcp, const float* __restrict__ icatW,
    const float* __restrict__ u2wbuf,
    const float* __restrict__ addrW, const float* __restrict__ addrWT,
    const float* __restrict__ atten, const float* __restrict__ Wm2w,
    const float* __restrict__ valHist,
    const int* __restrict__ lastWriter, const int* __restrict__ writePos,
    float* __restrict__ zbuf, float* __restrict__ gmaxv, int* __restrict__ gmaxi,
    int t) {
  const int b = blockIdx.x >> 2, ch = blockIdx.x & 3, nbase = ch * 128;
  const int tid = threadIdx.x;
  __shared__ float bias[AC], att[AC], zch[128], sred[256], vst[CCd];
  __shared__ float mred[2]; __shared__ int mredi[2];
  const size_t row = (size_t)t * BB + b;
  uint32_t k1a, k1b;
  threefry2x32(0u, 42u, 0u, 0u, k1a, k1b);
  bias[tid] = hcp[(size_t)b * WC + COL_W0 + tid] + hcp[(size_t)(BB + b) * WC + COL_W0 + tid]
            + icatW[row * AC + tid] + u2wbuf[(size_t)b * AC + tid];
  att[tid] = atten[tid];
  __syncthreads();
  {  // logits: 128 slots x 2 k-halves
    int nl = tid & 127, kh = tid >> 7;
    int n = nbase + nl;
    float p = 0.0f; int k0 = kh * 128;
    const float* awc = addrWT + n;
#pragma unroll 8
    for (int k = k0; k < k0 + 128; ++k)
      p = fmaf(fast_tanh(bias[k] + awc[(size_t)k * NS]), att[k], p);
    sred[tid] = p;
  }
  __syncthreads();
  if (tid < 128) zch[tid] = sred[tid] + sred[tid + 128];
  __syncthreads();
  // corrections for written slots in this chunk (on-the-fly val@Wm2w delta)
  for (int j = 0; j < t; ++j) {
    int n2 = writePos[b * LL + j];
    if (n2 < nbase || n2 >= nbase + 128) continue;
    int s = lastWriter[b * NS + n2];
    if (tid < CCd) vst[tid] = valHist[((size_t)b * LL + s) * CCd + tid];
    __syncthreads();
    float delta = 0.0f;
#pragma unroll 8
    for (int c = 0; c < CCd; ++c)
      delta = fmaf(vst[c], Wm2w[(size_t)(AA + c) * AC + tid], delta);
    sred[tid] = fast_tanh(bias[tid] + addrW[(size_t)n2 * AC + tid] + delta) * att[tid];
    __syncthreads();
    if (tid < 128) sred[tid] += sred[tid + 128];
    __syncthreads();
    if (tid < 64) {
      float q = sred[tid] + sred[tid + 64];
      for (int off = 32; off; off >>= 1) q += __shfl_down(q, off, 64);
      if (tid == 0) zch[n2 - nbase] = q;
    }
    __syncthreads();
  }
  // gumbel + chunk argmax
  float zg2 = -1e30f; int ig2 = 0x7fffffff;
  if (tid < 128) {
    int n = nbase + tid;
    uint32_t gi = (uint32_t)(row * NS + n);
    uint32_t o0, o1; threefry2x32(k1a, k1b, 0u, gi, o0, o1);
    float zg = zch[tid] + bits_to_gumbel(o0 ^ o1);
    zbuf[(size_t)b * NS + n] = zg;
    zg2 = zg; ig2 = n;
  }
  for (int off = 32; off; off >>= 1) {
    float vo = __shfl_down(zg2, off, 64); int io = __shfl_down(ig2, off, 64);
    if (vo > zg2 || (vo == zg2 && io < ig2)) { zg2 = vo; ig2 = io; }
  }
  if (tid < 128 && (tid & 63) == 0) { mred[tid >> 6] = zg2; mredi[tid >> 6] = ig2; }
  __syncthreads();
  if (tid == 0) {
    float v = mred[0]; int ix = mredi[0];
    if (mred[1] > v || (mred[1] == v && mredi[1] < ix)) { v = mred[1]; ix = mredi[1]; }
    gmaxv[b * 4 + ch] = v; gmaxi[b * 4 + ch] = ix;
  }
}

// ------------------- K3: select / r / gates / ab / bookkeeping -------------
__global__ __launch_bounds__(512) void k3_select(
    const float* __restrict__ zbuf, const float* __restrict__ gmaxv,
    const int* __restrict__ gmaxi, const float* __restrict__ hcp,
    const float* __restrict__ icatG, const float* __restrict__ b_h2tau,
    const float* __restrict__ mem_bias, const float* __restrict__ valHist,
    const float* __restrict__ Wr2g, const float* __restrict__ Wr2ab,
    int* __restrict__ lastWriter, int* __restrict__ writePos,
    float* __restrict__ w_sum, float* __restrict__ rsbuf,
    float* __restrict__ fiobuf, float* __restrict__ abbuf, int t) {
  const int b = blockIdx.x, tid = threadIdx.x;
  const int lane = tid & 63, wv = tid >> 6;
  __shared__ float rs[AC], redv[8];
  __shared__ float s_tau, s_zmax, s_ws; __shared__ int s_ns;
  const size_t row = (size_t)t * BB + b;
  uint32_t k2a, k2b;
  threefry2x32(0u, 42u, 0u, 1u, k2a, k2b);
  if (tid == 0) {
    float v = gmaxv[b * 4]; int ix = gmaxi[b * 4];
#pragma unroll
    for (int i = 1; i < 4; ++i) {
      float vi = gmaxv[b * 4 + i]; int ii = gmaxi[b * 4 + i];
      if (vi > v || (vi == v && ii < ix)) { v = vi; ix = ii; }
    }
    s_zmax = v; s_ns = ix;
    float x = hcp[(size_t)b * WC + COL_TAU] + hcp[(size_t)(BB + b) * WC + COL_TAU] + b_h2tau[0];
    s_tau = fmaxf(x, 0.0f) + log1pf(expf(-fabsf(x))) + 1.0f;
  }
  __syncthreads();
  {
    float e = expf((zbuf[(size_t)b * NS + tid] - s_zmax) / s_tau);
    for (int off = 32; off; off >>= 1) e += __shfl_down(e, off, 64);
    if (lane == 0) redv[wv] = e;
  }
  __syncthreads();
  if (tid == 0) {
    float D = 0;
#pragma unroll
    for (int i = 0; i < 8; ++i) D += redv[i];
    float ystar = 1.0f / D;
    s_ws = (1.0f - ystar) + ystar;
  }
  __syncthreads();
  const int ns = s_ns; const float ws = s_ws;
  if (tid < AC) {
    int sW = lastWriter[b * NS + ns];
    float mv = (tid < AA) ? mem_bias[(size_t)ns * AC + tid]
             : ((sW >= 0) ? valHist[((size_t)b * LL + sW) * CCd + tid - AA] : 0.0f);
    float rv = ws * mv;
    rs[tid] = rv;
    rsbuf[(size_t)b * AC + tid] = rv;
  }
  __syncthreads();
  if (tid == 0) {   // bookkeeping AFTER r-gather read lastWriter
    int pos = (t < 16) ? t * LL : ns;
    writePos[b * LL + t] = pos;
    lastWriter[b * NS + pos] = t;
    w_sum[(size_t)b * NS + ns] += ws;
  }
  if (wv >= 1 && wv <= 5) {
    int j = wv - 1;
    float p = 0.0f;
    if (j < 3) { for (int k = lane; k < AC; k += 64) p = fmaf(rs[k], Wr2g[k * 3 + j], p); }
    else { int jj = j - 3; for (int k = lane; k < AC; k += 64) p = fmaf(rs[k], Wr2ab[k * 2 + jj], p); }
    for (int off = 32; off; off >>= 1) p += __shfl_down(p, off, 64);
    if (lane == 0) {
      float hterm = hcp[(size_t)b * WC + COL_G0 + j] + hcp[(size_t)(BB + b) * WC + COL_G0 + j];
      float x = p + hterm + icatG[row * 5 + j];
      if (j < 3) {
        fiobuf[b * 3 + j] = 1.0f / (1.0f + expf(-x));
      } else {
        int jj = j - 3;
        uint32_t i1 = (uint32_t)((row * 2 + jj) * 2);
        uint32_t o0, o1;
        threefry2x32(k2a, k2b, 0u, i1, o0, o1);     float g1 = bits_to_gumbel(o0 ^ o1);
        threefry2x32(k2a, k2b, 0u, i1 + 1, o0, o1); float g2 = bits_to_gumbel(o0 ^ o1);
        abbuf[b * 2 + jj] = (x + g1 - g2) > 0.0f ? 1.0f : 0.0f;
      }
    }
  }
}

// ------------------- K4: LSTM update || LayerNorm(w_sum) -------------------
__global__ __launch_bounds__(256) void k4_update(
    const float* __restrict__ rsbuf, const float* __restrict__ fiobuf,
    const float* __restrict__ abbuf, const float* __restrict__ hcp,
    const float* __restrict__ icatC, const float* __restrict__ Wr2c,
    float* __restrict__ ccbuf, float* __restrict__ hbuf,
    float* __restrict__ out, const float* __restrict__ w_sum,
    float* __restrict__ zlbuf, int t) {
  const int blk = blockIdx.x, tid = threadIdx.x;
  if (blk < 512) {
    const int b = blk >> 2, q = blk & 3, c = q * 256 + tid;
    __shared__ float rs[AC];
    rs[tid] = rsbuf[(size_t)b * AC + tid];
    __syncthreads();
    const float fg = fiobuf[b * 3], ig = fiobuf[b * 3 + 1], og = fiobuf[b * 3 + 2];
    const float alpha = abbuf[b * 2], beta = abbuf[b * 2 + 1];
    const size_t row = (size_t)t * BB + b;
    float rc = 0.0f;
    if (alpha != 0.0f) {
      const float* wp = Wr2c + c;
      float a0 = 0, a1 = 0, a2 = 0, a3 = 0;
#pragma unroll 4
      for (int k = 0; k < AC; k += 4) {
        a0 = fmaf(rs[k + 0], wp[(size_t)(k + 0) * HD], a0);
        a1 = fmaf(rs[k + 1], wp[(size_t)(k + 1) * HD], a1);
        a2 = fmaf(rs[k + 2], wp[(size_t)(k + 2) * HD], a2);
        a3 = fmaf(rs[k + 3], wp[(size_t)(k + 3) * HD], a3);
      }
      rc = (a0 + a1) + (a2 + a3);
    }
    float hcterm = (beta != 0.0f)
        ? (hcp[(size_t)b * WC + c] + hcp[(size_t)(BB + b) * WC + c]) : 0.0f;
    float arg = beta * hcterm + icatC[row * HD + c] + alpha * rc;
    float cn = fg * ccbuf[(size_t)b * HD + c] + ig * tanhf(arg);
    float hn = og * tanhf(cn);
    ccbuf[(size_t)b * HD + c] = cn;
    hbuf[(size_t)b * HD + c] = hn;
    out[row * HD + c] = hn;
  } else {
    const int b = blk - 512;
    const int lane = tid & 63, wv = tid >> 6;
    __shared__ float red[4];
    float v0 = w_sum[(size_t)b * NS + tid];
    float v1 = w_sum[(size_t)b * NS + 256 + tid];
    float s1 = v0 + v1;
    for (int off = 32; off; off >>= 1) s1 += __shfl_down(s1, off, 64);
    if (lane == 0) red[wv] = s1;
    __syncthreads();
    float mu = (red[0] + red[1] + red[2] + red[3]) / (float)NS;
    __syncthreads();
    float d = (v0 - mu) * (v0 - mu) + (v1 - mu) * (v1 - mu);
    for (int off = 32; off; off >>= 1) d += __shfl_down(d, off, 64);
    if (lane == 0) red[wv] = d;
    __syncthreads();
    float var = (red[0] + red[1] + red[2] + red[3]) / (float)NS;
    float rsq = rsqrtf(var + 1e-5f);
    zlbuf[(size_t)b * NS + tid] = (v0 - mu) * rsq;
    zlbuf[(size_t)b * NS + 256 + tid] = (v1 - mu) * rsq;
  }
}

// ------------------------------ host ---------------------------------------
extern "C" void kernel_launch(void* const* d_in, const int* in_sizes, int n_in,
                              void* d_out, int out_size, void* d_ws, size_t ws_size,
                              hipStream_t stream) {
  const float* inp      = (const float*)d_in[0];
  const float* hid      = (const float*)d_in[1];
  const float* mem_bias = (const float*)d_in[2];
  const float* W_h2w    = (const float*)d_in[3];
  const float* W_i2w    = (const float*)d_in[4];
  const float* W_m2w    = (const float*)d_in[5];
  const float* W_u2w    = (const float*)d_in[6];
  const float* W_h2g    = (const float*)d_in[7];
  const float* W_i2g    = (const float*)d_in[8];
  const float* W_r2g    = (const float*)d_in[9];
  const float* W_h2ab   = (const float*)d_in[10];
  const float* W_i2ab   = (const float*)d_in[11];
  const float* W_r2ab   = (const float*)d_in[12];
  const float* W_h2c    = (const float*)d_in[13];
  const float* W_i2c    = (const float*)d_in[14];
  const float* W_r2c    = (const float*)d_in[15];
  const float* atten    = (const float*)d_in[16];
  const float* W_h2tau  = (const float*)d_in[17];
  const float* b_h2tau  = (const float*)d_in[18];
  const float* W_h2m    = (const float*)d_in[19];
  float* out = (float*)d_out;

  char* base = (char*)d_ws;
  size_t off = 0;
  auto alloc = [&](size_t elems) -> void* {
    void* p = (void*)(base + off);
    off += ((elems * 4 + 255) / 256) * 256;
    return p;
  };
  float* icatC   = (float*)alloc((size_t)LL * BB * HD);
  float* icatW   = (float*)alloc((size_t)LL * BB * AC);
  float* icatG   = (float*)alloc((size_t)LL * BB * 5);
  float* Wcat    = (float*)alloc((size_t)HD * WC);
  float* addrW   = (float*)alloc((size_t)NS * AC);
  float* addrWT  = (float*)alloc((size_t)NS * AC);
  float* hbuf    = (float*)alloc((size_t)BB * HD);
  float* ccbuf   = (float*)alloc((size_t)BB * HD);
  float* w_sum   = (float*)alloc((size_t)BB * NS);
  float* zlbuf   = (float*)alloc((size_t)BB * NS);
  float* u2wbuf  = (float*)alloc((size_t)BB * AC);
  float* hcp     = (float*)alloc((size_t)2 * BB * WC);
  float* zbuf    = (float*)alloc((size_t)BB * NS);
  float* gmaxv   = (float*)alloc((size_t)BB * 4);
  float* rsbuf   = (float*)alloc((size_t)BB * AC);
  float* fiobuf  = (float*)alloc((size_t)BB * 3);
  float* abbuf   = (float*)alloc((size_t)BB * 2);
  float* valHist = (float*)alloc((size_t)BB * LL * CCd);
  int*   gmaxi   = (int*)alloc((size_t)BB * 4);
  int*   lastWriter = (int*)alloc((size_t)BB * NS);
  int*   writePos   = (int*)alloc((size_t)BB * LL);

  hipLaunchKernelGGL(pack_wcat, dim3((HD * WC + 255) / 256), dim3(256), 0, stream,
                     W_h2c, W_h2w, W_h2g, W_h2ab, W_h2tau, Wcat);
  hipLaunchKernelGGL(addrw_kernel, dim3((NS * AC + 255) / 256), dim3(256), 0, stream,
                     mem_bias, W_m2w, addrW, addrWT);
  hipLaunchKernelGGL(icatg_kernel, dim3((LL * BB * 5 + 255) / 256), dim3(256), 0, stream,
                     inp, W_i2g, W_i2ab, icatG);
  hipLaunchKernelGGL(init_kernel, dim3((BB * HD + 255) / 256), dim3(256), 0, stream,
                     hid, hbuf, ccbuf, w_sum, zlbuf, lastWriter);
  hipLaunchKernelGGL(gemm_big, dim3((LL * BB) / 128, HD / 64), dim3(256), 0, stream,
                     inp, W_i2c, icatC, ID, HD);
  hipLaunchKernelGGL(gemm_big, dim3((LL * BB) / 128, AC / 64), dim3(256), 0, stream,
                     inp, W_i2w, icatW, ID, AC);

  for (int t = 0; t < LL; ++t) {
    hipLaunchKernelGGL(k1_pre, dim3(384), dim3(256), 0, stream,
                       hbuf, Wcat, W_h2m, zlbuf, W_u2w, hcp, valHist, u2wbuf, t);
    hipLaunchKernelGGL(k2_logits, dim3(512), dim3(256), 0, stream,
                       hcp, icatW, u2wbuf, addrW, addrWT, atten, W_m2w, valHist,
                       lastWriter, writePos, zbuf, gmaxv, gmaxi, t);
    hipLaunchKernelGGL(k3_select, dim3(BB), dim3(512), 0, stream,
                       zbuf, gmaxv, gmaxi, hcp, icatG, b_h2tau, mem_bias, valHist,
                       W_r2g, W_r2ab, lastWriter, writePos, w_sum,
                       rsbuf, fiobuf, abbuf, t);
    hipLaunchKernelGGL(k4_update, dim3(640), dim3(256), 0, stream,
                       rsbuf, fiobuf, abbuf, hcp, icatC, W_r2c,
                       ccbuf, hbuf, out, w_sum, zlbuf, t);
  }
}